// Round 1
// baseline (353.884 us; speedup 1.0000x reference)
//
#include <hip/hip_runtime.h>

typedef unsigned short u16;
typedef unsigned int u32;
typedef __attribute__((ext_vector_type(8))) short s16x8;   // 8 bf16 (4 VGPR) MFMA frag
typedef __attribute__((ext_vector_type(4))) float f32x4;
typedef __attribute__((ext_vector_type(4))) u32 u32x4;
typedef __attribute__((ext_vector_type(4))) float fvec4;

#define DEV static __device__ __forceinline__

DEV u16 f2bf(float f){
  u32 u = __builtin_bit_cast(u32, f);
  u32 r = (u + 0x7FFFu + ((u >> 16) & 1u)) >> 16;
  return (u16)r;
}
DEV float bf2f(u16 v){
  u32 x = ((u32)v) << 16;
  return __builtin_bit_cast(float, x);
}
DEV f32x4 mfma16(s16x8 a, s16x8 b, f32x4 c){
  return __builtin_amdgcn_mfma_f32_16x16x32_bf16(a, b, c, 0, 0, 0);
}
DEV s16x8 ld16B(const u16* p){
  return __builtin_bit_cast(s16x8, *(const u32x4*)p);
}

// Problem sizes: B=8 NT=1569 DIM=768 H=12 D=64 BH=96 F=8 NQ=196 M=12552 Nqkv=2304 K=768

// ---------------- conversion kernels ----------------
__global__ __launch_bounds__(256) void k_cvt(const float* __restrict__ in, u16* __restrict__ out, int n4){
  int i = blockIdx.x*256 + threadIdx.x;
  int stride = gridDim.x*256;
  for (; i < n4; i += stride){
    fvec4 v = ((const fvec4*)in)[i];
    u16 o0 = f2bf(v[0]), o1 = f2bf(v[1]), o2 = f2bf(v[2]), o3 = f2bf(v[3]);
    u32 lo = (u32)o0 | ((u32)o1 << 16);
    u32 hi = (u32)o2 | ((u32)o3 << 16);
    ((u32*)out)[2*i]   = lo;
    ((u32*)out)[2*i+1] = hi;
  }
}

// W[K][N] f32 -> WT[N][K] bf16
__global__ __launch_bounds__(256) void k_transpose(const float* __restrict__ W, u16* __restrict__ WT, int K, int N){
  int i = blockIdx.x*256 + threadIdx.x;
  int stride = gridDim.x*256;
  int total = K*N;
  for (; i < total; i += stride){
    int n = i / K, k = i - n*K;
    WT[i] = f2bf(W[(size_t)k*N + n]);
  }
}

// ---------------- QKV GEMM: [12552x768] @ [768x2304] -> scatter q,k,v (bh,t,d) bf16 ----------------
__global__ __launch_bounds__(256) void gemm_qkv(const u16* __restrict__ A, const u16* __restrict__ BT,
                                                u16* __restrict__ qout, u16* __restrict__ kout, u16* __restrict__ vout){
  __shared__ u16 As[128][72];
  __shared__ u16 Bs[128][72];
  const int M = 12552;
  int tid = threadIdx.x;
  int w = tid >> 6, l = tid & 63, l15 = l & 15, l4 = l >> 4;
  int wr = w >> 1, wc = w & 1;
  int bm = blockIdx.y * 128, bn = blockIdx.x * 128;
  f32x4 acc[4][4];
  #pragma unroll
  for (int a=0;a<4;a++)
    #pragma unroll
    for (int b=0;b<4;b++) acc[a][b] = (f32x4){0.f,0.f,0.f,0.f};

  int lr = tid >> 3;          // 0..31
  int cc = (tid & 7) * 8;     // 0..56

  for (int kt = 0; kt < 12; kt++){
    #pragma unroll
    for (int p = 0; p < 4; p++){
      int row = lr + p*32;
      int gr = bm + row;
      u32x4 av = {0,0,0,0};
      if (gr < M) av = *(const u32x4*)(A + (size_t)gr*768 + kt*64 + cc);
      *(u32x4*)&As[row][cc] = av;
      u32x4 bv = *(const u32x4*)(BT + (size_t)(bn + row)*768 + kt*64 + cc);
      *(u32x4*)&Bs[row][cc] = bv;
    }
    __syncthreads();
    #pragma unroll
    for (int kk = 0; kk < 2; kk++){
      s16x8 af[4], bfr[4];
      #pragma unroll
      for (int mt=0; mt<4; mt++) af[mt]  = ld16B(&As[wr*64 + mt*16 + l15][kk*32 + l4*8]);
      #pragma unroll
      for (int nt=0; nt<4; nt++) bfr[nt] = ld16B(&Bs[wc*64 + nt*16 + l15][kk*32 + l4*8]);
      #pragma unroll
      for (int mt=0; mt<4; mt++)
        #pragma unroll
        for (int nt=0; nt<4; nt++)
          acc[mt][nt] = mfma16(af[mt], bfr[nt], acc[mt][nt]);
    }
    __syncthreads();
  }

  // epilogue: scatter to q/k/v (bh-major) layout, scale q by 0.125
  #pragma unroll
  for (int mt=0; mt<4; mt++){
    #pragma unroll
    for (int r=0; r<4; r++){
      int m = bm + wr*64 + mt*16 + l4*4 + r;
      if (m >= M) continue;
      int b = m / 1569, t = m - b*1569;
      #pragma unroll
      for (int nt=0; nt<4; nt++){
        int n = bn + wc*64 + nt*16 + l15;
        int which = n / 768;
        int rem = n - which*768;
        int h = rem >> 6, d = rem & 63;
        float v = acc[mt][nt][r];
        if (which == 0) v *= 0.125f;
        u16* dst = (which==0) ? qout : ((which==1) ? kout : vout);
        dst[((size_t)(b*12 + h)*1569 + t)*64 + d] = f2bf(v);
      }
    }
  }
}

// ---------------- CLS attention: 96 blocks, full softmax over 1569 keys ----------------
__global__ __launch_bounds__(256) void k_cls(const u16* __restrict__ qb, const u16* __restrict__ kb,
                                             const u16* __restrict__ vb, u16* __restrict__ ob,
                                             float* __restrict__ attn){
  int g = blockIdx.x;
  int tid = threadIdx.x;
  __shared__ float qv[64];
  __shared__ float sim[1569];
  __shared__ float red[256];
  const u16* qr = qb + (size_t)g*1569*64;
  if (tid < 64) qv[tid] = bf2f(qr[tid]);
  __syncthreads();
  float lmax = -1e30f;
  for (int j = tid; j < 1569; j += 256){
    const u16* kr = kb + ((size_t)g*1569 + j)*64;
    float s = 0.f;
    #pragma unroll
    for (int d0 = 0; d0 < 64; d0 += 8){
      u32x4 u = *(const u32x4*)(kr + d0);
      const u16* us = (const u16*)&u;
      #pragma unroll
      for (int i=0;i<8;i++) s += qv[d0+i]*bf2f(us[i]);
    }
    sim[j] = s;
    lmax = fmaxf(lmax, s);
  }
  red[tid] = lmax; __syncthreads();
  for (int st=128; st>0; st>>=1){ if (tid<st) red[tid] = fmaxf(red[tid], red[tid+st]); __syncthreads(); }
  float mx = red[0]; __syncthreads();
  float lsum = 0.f;
  for (int j = tid; j < 1569; j += 256){
    float e = expf(sim[j]-mx); sim[j] = e; lsum += e;
  }
  red[tid] = lsum; __syncthreads();
  for (int st=128; st>0; st>>=1){ if (tid<st) red[tid] += red[tid+st]; __syncthreads(); }
  float invS = 1.f/red[0]; __syncthreads();
  for (int j = tid; j < 1569; j += 256){
    float p = sim[j]*invS; sim[j] = p; attn[(size_t)g*1569 + j] = p;
  }
  __syncthreads();
  int d = tid & 63, part = tid >> 6;
  float a = 0.f;
  for (int j = part; j < 1569; j += 4) a += sim[j]*bf2f(vb[((size_t)g*1569 + j)*64 + d]);
  red[tid] = a; __syncthreads();
  if (tid < 64) ob[(size_t)g*1569*64 + tid] = f2bf(red[tid]+red[tid+64]+red[tid+128]+red[tid+192]);
}

// ---------------- frame attention: 768 groups, 196 q x 197 kv x 64d, flash-style ----------------
__global__ __launch_bounds__(256) void k_frame(const u16* __restrict__ qb, const u16* __restrict__ kb,
                                               const u16* __restrict__ vb, u16* __restrict__ ob){
  int g = blockIdx.x;              // 0..767
  int bh = g >> 3, fi = g & 7;
  int tid = threadIdx.x;
  int w = tid >> 6, l = tid & 63;
  int l15 = l & 15, l4 = l >> 4;

  __shared__ u16 Ks[32][72];       // K block, padded
  __shared__ u16 Vt[64][40];       // V block transposed [d][key], padded
  __shared__ u16 Ps[4][64][40];    // per-wave P tile [qrow][key], padded

  const u16* qg = qb + ((size_t)bh*1569 + 1 + fi*196)*64;
  const u16* kg = kb + (size_t)bh*1569*64;
  const u16* vg = vb + (size_t)bh*1569*64;

  // Q fragments in registers (rows w*64 .. w*64+63; masked >=196)
  s16x8 qf[4][2];
  #pragma unroll
  for (int mt=0; mt<4; mt++){
    int row = w*64 + mt*16 + l15;
    #pragma unroll
    for (int kk=0; kk<2; kk++){
      if (row < 196) qf[mt][kk] = ld16B(qg + (size_t)row*64 + kk*32 + l4*8);
      else { u32x4 z = {0,0,0,0}; qf[mt][kk] = __builtin_bit_cast(s16x8, z); }
    }
  }

  f32x4 acc[4][4];
  float mrun[4][4], lrun[4][4];
  #pragma unroll
  for (int a=0;a<4;a++)
    #pragma unroll
    for (int b=0;b<4;b++){ acc[a][b] = (f32x4){0.f,0.f,0.f,0.f}; mrun[a][b] = -1e30f; lrun[a][b] = 0.f; }

  for (int kbk = 0; kbk < 7; kbk++){
    __syncthreads();
    {
      int jj = tid >> 3, c = (tid & 7)*8;
      int j = kbk*32 + jj;
      u32x4 kv = {0,0,0,0}, vv = {0,0,0,0};
      if (j < 197){
        int t = (j == 0) ? 0 : (1 + fi*196 + j - 1);
        kv = *(const u32x4*)(kg + (size_t)t*64 + c);
        vv = *(const u32x4*)(vg + (size_t)t*64 + c);
      }
      *(u32x4*)&Ks[jj][c] = kv;
      const u16* vp = (const u16*)&vv;
      #pragma unroll
      for (int i=0;i<8;i++) Vt[c+i][jj] = vp[i];
    }
    __syncthreads();

    s16x8 kf[2][2];
    #pragma unroll
    for (int nt=0; nt<2; nt++)
      #pragma unroll
      for (int kk=0; kk<2; kk++)
        kf[nt][kk] = ld16B(&Ks[nt*16 + l15][kk*32 + l4*8]);

    int key0 = kbk*32 + l15;
    bool bad0 = (key0 >= 197), bad1 = (key0 + 16 >= 197);

    #pragma unroll
    for (int mt=0; mt<4; mt++){
      f32x4 s0 = (f32x4){0.f,0.f,0.f,0.f}, s1 = (f32x4){0.f,0.f,0.f,0.f};
      s0 = mfma16(qf[mt][0], kf[0][0], s0);
      s0 = mfma16(qf[mt][1], kf[0][1], s0);
      s1 = mfma16(qf[mt][0], kf[1][0], s1);
      s1 = mfma16(qf[mt][1], kf[1][1], s1);
      #pragma unroll
      for (int r=0; r<4; r++){
        if (bad0) s0[r] = -1e30f;
        if (bad1) s1[r] = -1e30f;
      }
      #pragma unroll
      for (int r=0; r<4; r++){
        float mx = fmaxf(s0[r], s1[r]);
        mx = fmaxf(mx, __shfl_xor(mx, 1));
        mx = fmaxf(mx, __shfl_xor(mx, 2));
        mx = fmaxf(mx, __shfl_xor(mx, 4));
        mx = fmaxf(mx, __shfl_xor(mx, 8));
        float mold = mrun[mt][r];
        float mnew = fmaxf(mold, mx);
        float alpha = expf(mold - mnew);
        float p0 = expf(s0[r] - mnew);
        float p1 = expf(s1[r] - mnew);
        float rs = p0 + p1;
        rs += __shfl_xor(rs, 1);
        rs += __shfl_xor(rs, 2);
        rs += __shfl_xor(rs, 4);
        rs += __shfl_xor(rs, 8);
        lrun[mt][r] = lrun[mt][r]*alpha + rs;
        mrun[mt][r] = mnew;
        #pragma unroll
        for (int ntd=0; ntd<4; ntd++) acc[mt][ntd][r] *= alpha;
        int prow = mt*16 + l4*4 + r;
        Ps[w][prow][l15]      = f2bf(p0);
        Ps[w][prow][16 + l15] = f2bf(p1);
      }
    }

    s16x8 vf[4];
    #pragma unroll
    for (int ntd=0; ntd<4; ntd++) vf[ntd] = ld16B(&Vt[ntd*16 + l15][l4*8]);
    #pragma unroll
    for (int mt=0; mt<4; mt++){
      s16x8 pf = ld16B(&Ps[w][mt*16 + l15][l4*8]);
      #pragma unroll
      for (int ntd=0; ntd<4; ntd++)
        acc[mt][ntd] = mfma16(pf, vf[ntd], acc[mt][ntd]);
    }
  }

  u16* og = ob + ((size_t)bh*1569 + 1 + fi*196)*64;
  #pragma unroll
  for (int mt=0; mt<4; mt++){
    #pragma unroll
    for (int r=0; r<4; r++){
      int row = w*64 + mt*16 + l4*4 + r;
      if (row < 196){
        float inv = 1.f / lrun[mt][r];
        #pragma unroll
        for (int ntd=0; ntd<4; ntd++)
          og[(size_t)row*64 + ntd*16 + l15] = f2bf(acc[mt][ntd][r] * inv);
      }
    }
  }
}

// ---------------- out GEMM: gather(attn_out) [12552x768] @ [768x768] + bias -> f32 ----------------
__global__ __launch_bounds__(256) void gemm_out(const u16* __restrict__ AO, const u16* __restrict__ BT,
                                                const float* __restrict__ bias, float* __restrict__ C){
  __shared__ u16 As[128][72];
  __shared__ u16 Bs[128][72];
  const int M = 12552;
  int tid = threadIdx.x;
  int w = tid >> 6, l = tid & 63, l15 = l & 15, l4 = l >> 4;
  int wr = w >> 1, wc = w & 1;
  int bm = blockIdx.y * 128, bn = blockIdx.x * 128;
  f32x4 acc[4][4];
  #pragma unroll
  for (int a=0;a<4;a++)
    #pragma unroll
    for (int b=0;b<4;b++) acc[a][b] = (f32x4){0.f,0.f,0.f,0.f};

  int lr = tid >> 3;
  int cc = (tid & 7) * 8;

  for (int kt = 0; kt < 12; kt++){     // kt == head index (BK=64 == one head)
    #pragma unroll
    for (int p = 0; p < 4; p++){
      int row = lr + p*32;
      int gr = bm + row;
      u32x4 av = {0,0,0,0};
      if (gr < M){
        int b = gr / 1569, t = gr - b*1569;
        av = *(const u32x4*)(AO + ((size_t)(b*12 + kt)*1569 + t)*64 + cc);
      }
      *(u32x4*)&As[row][cc] = av;
      u32x4 bv = *(const u32x4*)(BT + (size_t)(bn + row)*768 + kt*64 + cc);
      *(u32x4*)&Bs[row][cc] = bv;
    }
    __syncthreads();
    #pragma unroll
    for (int kk = 0; kk < 2; kk++){
      s16x8 af[4], bfr[4];
      #pragma unroll
      for (int mt=0; mt<4; mt++) af[mt]  = ld16B(&As[wr*64 + mt*16 + l15][kk*32 + l4*8]);
      #pragma unroll
      for (int nt=0; nt<4; nt++) bfr[nt] = ld16B(&Bs[wc*64 + nt*16 + l15][kk*32 + l4*8]);
      #pragma unroll
      for (int mt=0; mt<4; mt++)
        #pragma unroll
        for (int nt=0; nt<4; nt++)
          acc[mt][nt] = mfma16(af[mt], bfr[nt], acc[mt][nt]);
    }
    __syncthreads();
  }

  #pragma unroll
  for (int mt=0; mt<4; mt++){
    #pragma unroll
    for (int r=0; r<4; r++){
      int m = bm + wr*64 + mt*16 + l4*4 + r;
      if (m >= M) continue;
      #pragma unroll
      for (int nt=0; nt<4; nt++){
        int n = bn + wc*64 + nt*16 + l15;
        C[(size_t)m*768 + n] = acc[mt][nt][r] + bias[n];
      }
    }
  }
}

extern "C" void kernel_launch(void* const* d_in, const int* in_sizes, int n_in,
                              void* d_out, int out_size, void* d_ws, size_t ws_size,
                              hipStream_t stream){
  (void)in_sizes; (void)n_in; (void)out_size;
  const float* x    = (const float*)d_in[0];
  const float* Wqkv = (const float*)d_in[1];
  const float* Wout = (const float*)d_in[2];
  const float* bout = (const float*)d_in[3];
  float* out0 = (float*)d_out;
  float* out1 = out0 + (size_t)12552*768;   // cls_attn (96*1569)

  char* ws = (char*)d_ws;
  size_t off = 0;
  auto alloc = [&](size_t bytes)->char*{
    char* p = ws + off;
    off += (bytes + 255) & ~(size_t)255;
    return p;
  };
  u16* xb    = (u16*)alloc((size_t)12552*768*2);
  u16* wqkvT = (u16*)alloc((size_t)2304*768*2);
  u16* woutT = (u16*)alloc((size_t)768*768*2);
  u16* qb    = (u16*)alloc((size_t)96*1569*64*2);
  u16* kbuf  = (u16*)alloc((size_t)96*1569*64*2);
  u16* vbuf  = (u16*)alloc((size_t)96*1569*64*2);
  u16* ao    = (u16*)alloc((size_t)96*1569*64*2);
  if (off > ws_size) return;   // workspace too small -> visible failure, no OOB writes

  k_cvt<<<2048, 256, 0, stream>>>(x, xb, 12552*768/4);
  k_transpose<<<2048, 256, 0, stream>>>(Wqkv, wqkvT, 768, 2304);
  k_transpose<<<1024, 256, 0, stream>>>(Wout, woutT, 768, 768);
  gemm_qkv<<<dim3(18, 99), 256, 0, stream>>>(xb, wqkvT, qb, kbuf, vbuf);
  k_cls<<<96, 256, 0, stream>>>(qb, kbuf, vbuf, ao, out1);
  k_frame<<<768, 256, 0, stream>>>(qb, kbuf, vbuf, ao);
  gemm_out<<<dim3(6, 99), 256, 0, stream>>>(ao, woutT, bout, out0);
}

// Round 2
// 291.590 us; speedup vs baseline: 1.2136x; 1.2136x over previous
//
#include <hip/hip_runtime.h>

typedef unsigned short u16;
typedef unsigned int u32;
typedef __attribute__((ext_vector_type(8))) short s16x8;   // 8 bf16 (4 VGPR) MFMA frag
typedef __attribute__((ext_vector_type(4))) float f32x4;
typedef __attribute__((ext_vector_type(4))) u32 u32x4;
typedef __attribute__((ext_vector_type(4))) float fvec4;

#define DEV static __device__ __forceinline__

typedef __attribute__((address_space(1))) unsigned char ga_u8;
typedef __attribute__((address_space(3))) unsigned char la_u8;

DEV u16 f2bf(float f){
  u32 u = __builtin_bit_cast(u32, f);
  u32 r = (u + 0x7FFFu + ((u >> 16) & 1u)) >> 16;
  return (u16)r;
}
DEV float bf2f(u16 v){
  u32 x = ((u32)v) << 16;
  return __builtin_bit_cast(float, x);
}
DEV f32x4 mfma16(s16x8 a, s16x8 b, f32x4 c){
  return __builtin_amdgcn_mfma_f32_16x16x32_bf16(a, b, c, 0, 0, 0);
}
DEV s16x8 ld16B(const u16* p){
  return __builtin_bit_cast(s16x8, *(const u32x4*)p);
}
// async global->LDS, 16B per lane; lds base must be wave-uniform, HW adds lane*16
DEV void gload16(const void* g, void* l){
  __builtin_amdgcn_global_load_lds((const ga_u8*)g, (la_u8*)l, 16, 0, 0);
}

// Problem sizes: B=8 NT=1569 DIM=768 H=12 D=64 BH=96 F=8 NQ=196 M=12552 Nqkv=2304 K=768

// ---------------- conversion kernels ----------------
__global__ __launch_bounds__(256) void k_cvt(const float* __restrict__ in, u16* __restrict__ out, int n4){
  int i = blockIdx.x*256 + threadIdx.x;
  int stride = gridDim.x*256;
  for (; i < n4; i += stride){
    fvec4 v = ((const fvec4*)in)[i];
    u16 o0 = f2bf(v[0]), o1 = f2bf(v[1]), o2 = f2bf(v[2]), o3 = f2bf(v[3]);
    u32 lo = (u32)o0 | ((u32)o1 << 16);
    u32 hi = (u32)o2 | ((u32)o3 << 16);
    ((u32*)out)[2*i]   = lo;
    ((u32*)out)[2*i+1] = hi;
  }
}

// W[K][N] f32 -> WT[N][K] bf16
__global__ __launch_bounds__(256) void k_transpose(const float* __restrict__ W, u16* __restrict__ WT, int K, int N){
  int i = blockIdx.x*256 + threadIdx.x;
  int stride = gridDim.x*256;
  int total = K*N;
  for (; i < total; i += stride){
    int n = i / K, k = i - n*K;
    WT[i] = f2bf(W[(size_t)k*N + n]);
  }
}

// ---------------- QKV GEMM: [12552x768] @ [768x2304] -> scatter q,k,v (bh,t,d) bf16 ----------------
// m97 structure: linear LDS tiles + global_load_lds width-16 staging.
__global__ __launch_bounds__(256) void gemm_qkv(const u16* __restrict__ A, const u16* __restrict__ BT,
                                                u16* __restrict__ qout, u16* __restrict__ kout, u16* __restrict__ vout){
  __shared__ u16 As[128*64];
  __shared__ u16 Bs[128*64];
  const int M = 12552;
  int tid = threadIdx.x;
  int w = tid >> 6, l = tid & 63, l15 = l & 15, l4 = l >> 4;
  int wr = w >> 1, wc = w & 1;
  int bm = blockIdx.y * 128, bn = blockIdx.x * 128;
  f32x4 acc[4][4];
  #pragma unroll
  for (int a=0;a<4;a++)
    #pragma unroll
    for (int b=0;b<4;b++) acc[a][b] = (f32x4){0.f,0.f,0.f,0.f};

  int srow = l >> 3;          // 0..7  (row within 8-row chunk)
  int scol = (l & 7) * 8;     // element col 0..56

  for (int kt = 0; kt < 12; kt++){
    #pragma unroll
    for (int p = 0; p < 4; p++){
      int i = w*4 + p;                 // chunk 0..15 (8 rows each)
      int row = i*8 + srow;
      int gr = bm + row; if (gr >= M) gr = M-1;    // clamp: no OOB, garbage rows never stored
      gload16(A  + (size_t)gr*768        + kt*64 + scol, &As[i*512]);
      gload16(BT + (size_t)(bn+row)*768  + kt*64 + scol, &Bs[i*512]);
    }
    __syncthreads();
    #pragma unroll
    for (int kk = 0; kk < 2; kk++){
      s16x8 af[4], bfr[4];
      #pragma unroll
      for (int mt=0; mt<4; mt++) af[mt]  = ld16B(&As[(wr*64 + mt*16 + l15)*64 + kk*32 + l4*8]);
      #pragma unroll
      for (int nt=0; nt<4; nt++) bfr[nt] = ld16B(&Bs[(wc*64 + nt*16 + l15)*64 + kk*32 + l4*8]);
      #pragma unroll
      for (int mt=0; mt<4; mt++)
        #pragma unroll
        for (int nt=0; nt<4; nt++)
          acc[mt][nt] = mfma16(af[mt], bfr[nt], acc[mt][nt]);
    }
    __syncthreads();
  }

  // epilogue: scatter to q/k/v (bh-major) layout, scale q by 0.125
  #pragma unroll
  for (int mt=0; mt<4; mt++){
    #pragma unroll
    for (int r=0; r<4; r++){
      int m = bm + wr*64 + mt*16 + l4*4 + r;
      if (m >= M) continue;
      int b = m / 1569, t = m - b*1569;
      #pragma unroll
      for (int nt=0; nt<4; nt++){
        int n = bn + wc*64 + nt*16 + l15;
        int which = n / 768;
        int rem = n - which*768;
        int h = rem >> 6, d = rem & 63;
        float v = acc[mt][nt][r];
        if (which == 0) v *= 0.125f;
        u16* dst = (which==0) ? qout : ((which==1) ? kout : vout);
        dst[((size_t)(b*12 + h)*1569 + t)*64 + d] = f2bf(v);
      }
    }
  }
}

// ---------------- CLS attention, parallelized ----------------
// pass 1: sim[g][j] = q[g].k[g][j]; per-chunk max
__global__ __launch_bounds__(256) void cls_sim(const u16* __restrict__ qb, const u16* __restrict__ kb,
                                               float* __restrict__ sim, float* __restrict__ bmax){
  int c = blockIdx.x, g = blockIdx.y;
  int tid = threadIdx.x;
  __shared__ float qv[64];
  __shared__ float red[256];
  if (tid < 64) qv[tid] = bf2f(qb[(size_t)g*1569*64 + tid]);
  __syncthreads();
  int j = c*256 + tid;
  float s = -1e30f;
  if (j < 1569){
    const u16* kr = kb + ((size_t)g*1569 + j)*64;
    float a = 0.f;
    #pragma unroll
    for (int d0 = 0; d0 < 64; d0 += 8){
      u32x4 u = *(const u32x4*)(kr + d0);
      const u16* us = (const u16*)&u;
      #pragma unroll
      for (int i=0;i<8;i++) a += qv[d0+i]*bf2f(us[i]);
    }
    s = a;
    sim[(size_t)g*1569 + j] = s;
  }
  red[tid] = s; __syncthreads();
  for (int st=128; st>0; st>>=1){ if (tid<st) red[tid] = fmaxf(red[tid], red[tid+st]); __syncthreads(); }
  if (tid == 0) bmax[g*8 + c] = red[0];
}

// pass 2: global max + exp-sum, write normalized probabilities (output #1)
__global__ __launch_bounds__(256) void cls_fin(float* __restrict__ sim, const float* __restrict__ bmax,
                                               float* __restrict__ attn){
  int g = blockIdx.x, tid = threadIdx.x;
  __shared__ float red[256];
  float m = -1e30f;
  #pragma unroll
  for (int c=0;c<7;c++) m = fmaxf(m, bmax[g*8+c]);
  float ls = 0.f;
  for (int j = tid; j < 1569; j += 256){
    float e = expf(sim[(size_t)g*1569+j] - m);
    sim[(size_t)g*1569+j] = e;
    ls += e;
  }
  red[tid] = ls; __syncthreads();
  for (int st=128; st>0; st>>=1){ if (tid<st) red[tid] += red[tid+st]; __syncthreads(); }
  float inv = 1.f/red[0];
  for (int j = tid; j < 1569; j += 256)
    attn[(size_t)g*1569+j] = sim[(size_t)g*1569+j]*inv;
}

// pass 3: partial PV per 256-key chunk
__global__ __launch_bounds__(256) void cls_pv(const float* __restrict__ attn, const u16* __restrict__ vb,
                                              float* __restrict__ pvp){
  int c = blockIdx.x, g = blockIdx.y;
  int tid = threadIdx.x;
  int d = tid & 63, kk = tid >> 6;
  __shared__ float red[256];
  float a = 0.f;
  for (int jj = kk; jj < 256; jj += 4){
    int j = c*256 + jj;
    if (j < 1569) a += attn[(size_t)g*1569+j] * bf2f(vb[((size_t)g*1569+j)*64 + d]);
  }
  red[tid] = a; __syncthreads();
  if (tid < 64) pvp[((size_t)g*7 + c)*64 + tid] = red[tid]+red[tid+64]+red[tid+128]+red[tid+192];
}

// pass 4: reduce partials -> CLS row of attention output
__global__ __launch_bounds__(64) void cls_pv_red(const float* __restrict__ pvp, u16* __restrict__ ob){
  int g = blockIdx.x, d = threadIdx.x;
  float s = 0.f;
  #pragma unroll
  for (int c=0;c<7;c++) s += pvp[((size_t)g*7+c)*64 + d];
  ob[(size_t)g*1569*64 + d] = f2bf(s);
}

// ---------------- frame attention: 768 groups, 196 q x 197 kv x 64d, flash-style ----------------
__global__ __launch_bounds__(256) void k_frame(const u16* __restrict__ qb, const u16* __restrict__ kb,
                                               const u16* __restrict__ vb, u16* __restrict__ ob){
  int g = blockIdx.x;              // 0..767
  int bh = g >> 3, fi = g & 7;
  int tid = threadIdx.x;
  int w = tid >> 6, l = tid & 63;
  int l15 = l & 15, l4 = l >> 4;

  __shared__ u16 Ks[32][72];       // K block, padded
  __shared__ u16 Vt[64][40];       // V block transposed [d][key], padded
  __shared__ u16 Ps[4][64][40];    // per-wave P tile [qrow][key], padded

  const u16* qg = qb + ((size_t)bh*1569 + 1 + fi*196)*64;
  const u16* kg = kb + (size_t)bh*1569*64;
  const u16* vg = vb + (size_t)bh*1569*64;

  // Q fragments in registers (rows w*64 .. w*64+63; masked >=196)
  s16x8 qf[4][2];
  #pragma unroll
  for (int mt=0; mt<4; mt++){
    int row = w*64 + mt*16 + l15;
    #pragma unroll
    for (int kk=0; kk<2; kk++){
      if (row < 196) qf[mt][kk] = ld16B(qg + (size_t)row*64 + kk*32 + l4*8);
      else { u32x4 z = {0,0,0,0}; qf[mt][kk] = __builtin_bit_cast(s16x8, z); }
    }
  }

  f32x4 acc[4][4];
  float mrun[4][4], lrun[4][4];
  #pragma unroll
  for (int a=0;a<4;a++)
    #pragma unroll
    for (int b=0;b<4;b++){ acc[a][b] = (f32x4){0.f,0.f,0.f,0.f}; mrun[a][b] = -1e30f; lrun[a][b] = 0.f; }

  for (int kbk = 0; kbk < 7; kbk++){
    __syncthreads();
    {
      int jj = tid >> 3, c = (tid & 7)*8;
      int j = kbk*32 + jj;
      u32x4 kv = {0,0,0,0}, vv = {0,0,0,0};
      if (j < 197){
        int t = (j == 0) ? 0 : (1 + fi*196 + j - 1);
        kv = *(const u32x4*)(kg + (size_t)t*64 + c);
        vv = *(const u32x4*)(vg + (size_t)t*64 + c);
      }
      *(u32x4*)&Ks[jj][c] = kv;
      const u16* vp = (const u16*)&vv;
      #pragma unroll
      for (int i=0;i<8;i++) Vt[c+i][jj] = vp[i];
    }
    __syncthreads();

    s16x8 kf[2][2];
    #pragma unroll
    for (int nt=0; nt<2; nt++)
      #pragma unroll
      for (int kk=0; kk<2; kk++)
        kf[nt][kk] = ld16B(&Ks[nt*16 + l15][kk*32 + l4*8]);

    int key0 = kbk*32 + l15;
    bool bad0 = (key0 >= 197), bad1 = (key0 + 16 >= 197);

    #pragma unroll
    for (int mt=0; mt<4; mt++){
      f32x4 s0 = (f32x4){0.f,0.f,0.f,0.f}, s1 = (f32x4){0.f,0.f,0.f,0.f};
      s0 = mfma16(qf[mt][0], kf[0][0], s0);
      s0 = mfma16(qf[mt][1], kf[0][1], s0);
      s1 = mfma16(qf[mt][0], kf[1][0], s1);
      s1 = mfma16(qf[mt][1], kf[1][1], s1);
      #pragma unroll
      for (int r=0; r<4; r++){
        if (bad0) s0[r] = -1e30f;
        if (bad1) s1[r] = -1e30f;
      }
      #pragma unroll
      for (int r=0; r<4; r++){
        float mx = fmaxf(s0[r], s1[r]);
        mx = fmaxf(mx, __shfl_xor(mx, 1));
        mx = fmaxf(mx, __shfl_xor(mx, 2));
        mx = fmaxf(mx, __shfl_xor(mx, 4));
        mx = fmaxf(mx, __shfl_xor(mx, 8));
        float mold = mrun[mt][r];
        float mnew = fmaxf(mold, mx);
        float alpha = expf(mold - mnew);
        float p0 = expf(s0[r] - mnew);
        float p1 = expf(s1[r] - mnew);
        float rs = p0 + p1;
        rs += __shfl_xor(rs, 1);
        rs += __shfl_xor(rs, 2);
        rs += __shfl_xor(rs, 4);
        rs += __shfl_xor(rs, 8);
        lrun[mt][r] = lrun[mt][r]*alpha + rs;
        mrun[mt][r] = mnew;
        #pragma unroll
        for (int ntd=0; ntd<4; ntd++) acc[mt][ntd][r] *= alpha;
        int prow = mt*16 + l4*4 + r;
        Ps[w][prow][l15]      = f2bf(p0);
        Ps[w][prow][16 + l15] = f2bf(p1);
      }
    }

    s16x8 vf[4];
    #pragma unroll
    for (int ntd=0; ntd<4; ntd++) vf[ntd] = ld16B(&Vt[ntd*16 + l15][l4*8]);
    #pragma unroll
    for (int mt=0; mt<4; mt++){
      s16x8 pf = ld16B(&Ps[w][mt*16 + l15][l4*8]);
      #pragma unroll
      for (int ntd=0; ntd<4; ntd++)
        acc[mt][ntd] = mfma16(pf, vf[ntd], acc[mt][ntd]);
    }
  }

  u16* og = ob + ((size_t)bh*1569 + 1 + fi*196)*64;
  #pragma unroll
  for (int mt=0; mt<4; mt++){
    #pragma unroll
    for (int r=0; r<4; r++){
      int row = w*64 + mt*16 + l4*4 + r;
      if (row < 196){
        float inv = 1.f / lrun[mt][r];
        #pragma unroll
        for (int ntd=0; ntd<4; ntd++)
          og[(size_t)row*64 + ntd*16 + l15] = f2bf(acc[mt][ntd][r] * inv);
      }
    }
  }
}

// ---------------- out GEMM: gather(attn_out) [12552x768] @ [768x768] + bias -> f32 ----------------
__global__ __launch_bounds__(256) void gemm_out(const u16* __restrict__ AO, const u16* __restrict__ BT,
                                                const float* __restrict__ bias, float* __restrict__ C){
  __shared__ u16 As[128*64];
  __shared__ u16 Bs[128*64];
  const int M = 12552;
  int tid = threadIdx.x;
  int w = tid >> 6, l = tid & 63, l15 = l & 15, l4 = l >> 4;
  int wr = w >> 1, wc = w & 1;
  int bm = blockIdx.y * 128, bn = blockIdx.x * 128;
  f32x4 acc[4][4];
  #pragma unroll
  for (int a=0;a<4;a++)
    #pragma unroll
    for (int b=0;b<4;b++) acc[a][b] = (f32x4){0.f,0.f,0.f,0.f};

  int srow = l >> 3;
  int scol = (l & 7) * 8;

  for (int kt = 0; kt < 12; kt++){     // kt == head index (BK=64 == one head)
    #pragma unroll
    for (int p = 0; p < 4; p++){
      int i = w*4 + p;
      int row = i*8 + srow;
      int gr = bm + row; if (gr >= M) gr = M-1;
      int b = gr / 1569, t = gr - b*1569;
      gload16(AO + ((size_t)(b*12 + kt)*1569 + t)*64 + scol, &As[i*512]);
      gload16(BT + (size_t)(bn+row)*768 + kt*64 + scol, &Bs[i*512]);
    }
    __syncthreads();
    #pragma unroll
    for (int kk = 0; kk < 2; kk++){
      s16x8 af[4], bfr[4];
      #pragma unroll
      for (int mt=0; mt<4; mt++) af[mt]  = ld16B(&As[(wr*64 + mt*16 + l15)*64 + kk*32 + l4*8]);
      #pragma unroll
      for (int nt=0; nt<4; nt++) bfr[nt] = ld16B(&Bs[(wc*64 + nt*16 + l15)*64 + kk*32 + l4*8]);
      #pragma unroll
      for (int mt=0; mt<4; mt++)
        #pragma unroll
        for (int nt=0; nt<4; nt++)
          acc[mt][nt] = mfma16(af[mt], bfr[nt], acc[mt][nt]);
    }
    __syncthreads();
  }

  #pragma unroll
  for (int mt=0; mt<4; mt++){
    #pragma unroll
    for (int r=0; r<4; r++){
      int m = bm + wr*64 + mt*16 + l4*4 + r;
      if (m >= M) continue;
      #pragma unroll
      for (int nt=0; nt<4; nt++){
        int n = bn + wc*64 + nt*16 + l15;
        C[(size_t)m*768 + n] = acc[mt][nt][r] + bias[n];
      }
    }
  }
}

extern "C" void kernel_launch(void* const* d_in, const int* in_sizes, int n_in,
                              void* d_out, int out_size, void* d_ws, size_t ws_size,
                              hipStream_t stream){
  (void)in_sizes; (void)n_in; (void)out_size;
  const float* x    = (const float*)d_in[0];
  const float* Wqkv = (const float*)d_in[1];
  const float* Wout = (const float*)d_in[2];
  const float* bout = (const float*)d_in[3];
  float* out0 = (float*)d_out;
  float* out1 = out0 + (size_t)12552*768;   // cls_attn (96*1569)

  char* ws = (char*)d_ws;
  size_t off = 0;
  auto alloc = [&](size_t bytes)->char*{
    char* p = ws + off;
    off += (bytes + 255) & ~(size_t)255;
    return p;
  };
  u16* xb    = (u16*)alloc((size_t)12552*768*2);
  u16* wqkvT = (u16*)alloc((size_t)2304*768*2);
  u16* woutT = (u16*)alloc((size_t)768*768*2);
  u16* qb    = (u16*)alloc((size_t)96*1569*64*2);
  u16* kbuf  = (u16*)alloc((size_t)96*1569*64*2);
  u16* vbuf  = (u16*)alloc((size_t)96*1569*64*2);
  u16* ao    = (u16*)alloc((size_t)96*1569*64*2);
  float* simw = (float*)alloc((size_t)96*1569*4);
  float* bmax = (float*)alloc((size_t)96*8*4);
  float* pvp  = (float*)alloc((size_t)96*7*64*4);
  if (off > ws_size) return;   // workspace too small -> visible failure, no OOB writes

  k_cvt<<<2048, 256, 0, stream>>>(x, xb, 12552*768/4);
  k_transpose<<<2048, 256, 0, stream>>>(Wqkv, wqkvT, 768, 2304);
  k_transpose<<<1024, 256, 0, stream>>>(Wout, woutT, 768, 768);
  gemm_qkv<<<dim3(18, 99), 256, 0, stream>>>(xb, wqkvT, qb, kbuf, vbuf);
  cls_sim<<<dim3(7, 96), 256, 0, stream>>>(qb, kbuf, simw, bmax);
  cls_fin<<<96, 256, 0, stream>>>(simw, bmax, out1);
  cls_pv<<<dim3(7, 96), 256, 0, stream>>>(out1, vbuf, pvp);
  cls_pv_red<<<96, 64, 0, stream>>>(pvp, ao);
  k_frame<<<768, 256, 0, stream>>>(qb, kbuf, vbuf, ao);
  gemm_out<<<dim3(6, 99), 256, 0, stream>>>(ao, woutT, bout, out0);
}

// Round 3
// 271.107 us; speedup vs baseline: 1.3053x; 1.0756x over previous
//
#include <hip/hip_runtime.h>

typedef unsigned short u16;
typedef unsigned int u32;
typedef __attribute__((ext_vector_type(8))) short s16x8;   // 8 bf16 (4 VGPR) MFMA frag
typedef __attribute__((ext_vector_type(4))) float f32x4;
typedef __attribute__((ext_vector_type(4))) u32 u32x4;
typedef __attribute__((ext_vector_type(4))) float fvec4;

#define DEV static __device__ __forceinline__

typedef __attribute__((address_space(1))) unsigned char ga_u8;
typedef __attribute__((address_space(3))) unsigned char la_u8;

DEV u16 f2bf(float f){
  u32 u = __builtin_bit_cast(u32, f);
  u32 r = (u + 0x7FFFu + ((u >> 16) & 1u)) >> 16;
  return (u16)r;
}
DEV float bf2f(u16 v){
  u32 x = ((u32)v) << 16;
  return __builtin_bit_cast(float, x);
}
DEV f32x4 mfma16(s16x8 a, s16x8 b, f32x4 c){
  return __builtin_amdgcn_mfma_f32_16x16x32_bf16(a, b, c, 0, 0, 0);
}
DEV s16x8 ld16B(const u16* p){
  return __builtin_bit_cast(s16x8, *(const u32x4*)p);
}
// async global->LDS, 16B per lane; lds base must be wave-uniform, HW adds lane*16
DEV void gload16(const void* g, void* l){
  __builtin_amdgcn_global_load_lds((const ga_u8*)g, (la_u8*)l, 16, 0, 0);
}
// bijective XCD-chunked remap (m204): hw assigns xcd = bid%8; give each XCD a
// contiguous chunk of logical tile ids so panel reuse stays in one L2.
DEV int xcd_chunk(int bid, int nwg){
  int q = nwg >> 3, r = nwg & 7;
  int xcd = bid & 7, lin = bid >> 3;
  return (xcd < r ? xcd*(q+1) : r*(q+1) + (xcd-r)*q) + lin;
}

// Problem sizes: B=8 NT=1569 DIM=768 H=12 D=64 BH=96 F=8 NQ=196 M=12552 Nqkv=2304 K=768

// ---------------- conversion kernels ----------------
__global__ __launch_bounds__(256) void k_cvt(const float* __restrict__ in, u16* __restrict__ out, int n4){
  int i = blockIdx.x*256 + threadIdx.x;
  int stride = gridDim.x*256;
  for (; i < n4; i += stride){
    fvec4 v = ((const fvec4*)in)[i];
    u16 o0 = f2bf(v[0]), o1 = f2bf(v[1]), o2 = f2bf(v[2]), o3 = f2bf(v[3]);
    u32 lo = (u32)o0 | ((u32)o1 << 16);
    u32 hi = (u32)o2 | ((u32)o3 << 16);
    ((u32*)out)[2*i]   = lo;
    ((u32*)out)[2*i+1] = hi;
  }
}

// W[K][N] f32 -> WT[N][K] bf16, LDS-tiled: coalesced reads AND writes.
// K, N multiples of 32 (768/2304/768).
__global__ __launch_bounds__(256) void k_transpose(const float* __restrict__ W, u16* __restrict__ WT, int K, int N){
  __shared__ float tile[32][33];
  int bn = blockIdx.x * 32;   // n base
  int bk = blockIdx.y * 32;   // k base
  int tx = threadIdx.x & 31, ty = threadIdx.x >> 5;   // 8 rows per pass
  #pragma unroll
  for (int r = ty; r < 32; r += 8)
    tile[r][tx] = W[(size_t)(bk + r)*N + bn + tx];
  __syncthreads();
  #pragma unroll
  for (int r = ty; r < 32; r += 8)
    WT[(size_t)(bn + r)*K + bk + tx] = f2bf(tile[tx][r]);
}

// ---------------- QKV GEMM: [12552x768] @ [768x2304] -> scatter q,k,v (bh,t,d) bf16 ----------------
// m97 structure: linear LDS tiles + global_load_lds width-16 staging + XCD chunking.
__global__ __launch_bounds__(256) void gemm_qkv(const u16* __restrict__ A, const u16* __restrict__ BT,
                                                u16* __restrict__ qout, u16* __restrict__ kout, u16* __restrict__ vout){
  __shared__ u16 As[128*64];
  __shared__ u16 Bs[128*64];
  const int M = 12552;
  const int NWG = 18*99;
  int logical = xcd_chunk(blockIdx.x, NWG);
  int bxi = logical % 18, byi = logical / 18;   // n fastest: same-A blocks share an XCD chunk
  int bm = byi * 128, bn = bxi * 128;

  int tid = threadIdx.x;
  int w = tid >> 6, l = tid & 63, l15 = l & 15, l4 = l >> 4;
  int wr = w >> 1, wc = w & 1;
  f32x4 acc[4][4];
  #pragma unroll
  for (int a=0;a<4;a++)
    #pragma unroll
    for (int b=0;b<4;b++) acc[a][b] = (f32x4){0.f,0.f,0.f,0.f};

  int srow = l >> 3;          // 0..7  (row within 8-row chunk)
  int scol = (l & 7) * 8;     // element col 0..56

  for (int kt = 0; kt < 12; kt++){
    #pragma unroll
    for (int p = 0; p < 4; p++){
      int i = w*4 + p;                 // chunk 0..15 (8 rows each)
      int row = i*8 + srow;
      int gr = bm + row; if (gr >= M) gr = M-1;    // clamp: no OOB, garbage rows never stored
      gload16(A  + (size_t)gr*768        + kt*64 + scol, &As[i*512]);
      gload16(BT + (size_t)(bn+row)*768  + kt*64 + scol, &Bs[i*512]);
    }
    __syncthreads();
    #pragma unroll
    for (int kk = 0; kk < 2; kk++){
      s16x8 af[4], bfr[4];
      #pragma unroll
      for (int mt=0; mt<4; mt++) af[mt]  = ld16B(&As[(wr*64 + mt*16 + l15)*64 + kk*32 + l4*8]);
      #pragma unroll
      for (int nt=0; nt<4; nt++) bfr[nt] = ld16B(&Bs[(wc*64 + nt*16 + l15)*64 + kk*32 + l4*8]);
      #pragma unroll
      for (int mt=0; mt<4; mt++)
        #pragma unroll
        for (int nt=0; nt<4; nt++)
          acc[mt][nt] = mfma16(af[mt], bfr[nt], acc[mt][nt]);
    }
    __syncthreads();
  }

  // epilogue: scatter to q/k/v (bh-major). bn is a multiple of 128 and 768 = 6*128,
  // so `which` (q/k/v) and head are block/thread constants — hoisted.
  int which = bn / 768;
  int col0  = bn - which*768 + wc*64;     // multiple of 64
  int h     = col0 >> 6;                  // constant per thread
  u16* dst  = (which==0) ? qout : ((which==1) ? kout : vout);
  float scale = (which==0) ? 0.125f : 1.f;
  #pragma unroll
  for (int mt=0; mt<4; mt++){
    #pragma unroll
    for (int r=0; r<4; r++){
      int m = bm + wr*64 + mt*16 + l4*4 + r;
      if (m >= M) continue;
      int b = m / 1569, t = m - b*1569;
      u16* drow = dst + ((size_t)(b*12 + h)*1569 + t)*64 + l15;
      #pragma unroll
      for (int nt=0; nt<4; nt++)
        drow[nt*16] = f2bf(acc[mt][nt][r] * scale);
    }
  }
}

// ---------------- CLS attention, parallelized ----------------
// pass 1: sim[g][j] = q[g].k[g][j]; per-chunk max
__global__ __launch_bounds__(256) void cls_sim(const u16* __restrict__ qb, const u16* __restrict__ kb,
                                               float* __restrict__ sim, float* __restrict__ bmax){
  int c = blockIdx.x, g = blockIdx.y;
  int tid = threadIdx.x;
  __shared__ float qv[64];
  __shared__ float red[256];
  if (tid < 64) qv[tid] = bf2f(qb[(size_t)g*1569*64 + tid]);
  __syncthreads();
  int j = c*256 + tid;
  float s = -1e30f;
  if (j < 1569){
    const u16* kr = kb + ((size_t)g*1569 + j)*64;
    float a = 0.f;
    #pragma unroll
    for (int d0 = 0; d0 < 64; d0 += 8){
      u32x4 u = *(const u32x4*)(kr + d0);
      const u16* us = (const u16*)&u;
      #pragma unroll
      for (int i=0;i<8;i++) a += qv[d0+i]*bf2f(us[i]);
    }
    s = a;
    sim[(size_t)g*1569 + j] = s;
  }
  red[tid] = s; __syncthreads();
  for (int st=128; st>0; st>>=1){ if (tid<st) red[tid] = fmaxf(red[tid], red[tid+st]); __syncthreads(); }
  if (tid == 0) bmax[g*8 + c] = red[0];
}

// pass 2: global max + exp-sum, write normalized probabilities (output #1)
__global__ __launch_bounds__(256) void cls_fin(float* __restrict__ sim, const float* __restrict__ bmax,
                                               float* __restrict__ attn){
  int g = blockIdx.x, tid = threadIdx.x;
  __shared__ float red[256];
  float m = -1e30f;
  #pragma unroll
  for (int c=0;c<7;c++) m = fmaxf(m, bmax[g*8+c]);
  float ls = 0.f;
  for (int j = tid; j < 1569; j += 256){
    float e = expf(sim[(size_t)g*1569+j] - m);
    sim[(size_t)g*1569+j] = e;
    ls += e;
  }
  red[tid] = ls; __syncthreads();
  for (int st=128; st>0; st>>=1){ if (tid<st) red[tid] += red[tid+st]; __syncthreads(); }
  float inv = 1.f/red[0];
  for (int j = tid; j < 1569; j += 256)
    attn[(size_t)g*1569+j] = sim[(size_t)g*1569+j]*inv;
}

// pass 3: partial PV per 256-key chunk
__global__ __launch_bounds__(256) void cls_pv(const float* __restrict__ attn, const u16* __restrict__ vb,
                                              float* __restrict__ pvp){
  int c = blockIdx.x, g = blockIdx.y;
  int tid = threadIdx.x;
  int d = tid & 63, kk = tid >> 6;
  __shared__ float red[256];
  float a = 0.f;
  for (int jj = kk; jj < 256; jj += 4){
    int j = c*256 + jj;
    if (j < 1569) a += attn[(size_t)g*1569+j] * bf2f(vb[((size_t)g*1569+j)*64 + d]);
  }
  red[tid] = a; __syncthreads();
  if (tid < 64) pvp[((size_t)g*7 + c)*64 + tid] = red[tid]+red[tid+64]+red[tid+128]+red[tid+192];
}

// pass 4: reduce partials -> CLS row of attention output
__global__ __launch_bounds__(64) void cls_pv_red(const float* __restrict__ pvp, u16* __restrict__ ob){
  int g = blockIdx.x, d = threadIdx.x;
  float s = 0.f;
  #pragma unroll
  for (int c=0;c<7;c++) s += pvp[((size_t)g*7+c)*64 + d];
  ob[(size_t)g*1569*64 + d] = f2bf(s);
}

// ---------------- frame attention: 768 groups, 196 q x 197 kv x 64d, flash-style ----------------
__global__ __launch_bounds__(256) void k_frame(const u16* __restrict__ qb, const u16* __restrict__ kb,
                                               const u16* __restrict__ vb, u16* __restrict__ ob){
  int g = blockIdx.x;              // 0..767
  int bh = g >> 3, fi = g & 7;
  int tid = threadIdx.x;
  int w = tid >> 6, l = tid & 63;
  int l15 = l & 15, l4 = l >> 4;

  __shared__ u16 Ks[32][72];       // K block, padded
  __shared__ u16 Vt[64][40];       // V block transposed [d][key], padded
  __shared__ u16 Ps[4][64][40];    // per-wave P tile [qrow][key], padded

  const u16* qg = qb + ((size_t)bh*1569 + 1 + fi*196)*64;
  const u16* kg = kb + (size_t)bh*1569*64;
  const u16* vg = vb + (size_t)bh*1569*64;

  // Q fragments in registers (rows w*64 .. w*64+63; masked >=196)
  s16x8 qf[4][2];
  #pragma unroll
  for (int mt=0; mt<4; mt++){
    int row = w*64 + mt*16 + l15;
    #pragma unroll
    for (int kk=0; kk<2; kk++){
      if (row < 196) qf[mt][kk] = ld16B(qg + (size_t)row*64 + kk*32 + l4*8);
      else { u32x4 z = {0,0,0,0}; qf[mt][kk] = __builtin_bit_cast(s16x8, z); }
    }
  }

  f32x4 acc[4][4];
  float mrun[4][4], lrun[4][4];
  #pragma unroll
  for (int a=0;a<4;a++)
    #pragma unroll
    for (int b=0;b<4;b++){ acc[a][b] = (f32x4){0.f,0.f,0.f,0.f}; mrun[a][b] = -1e30f; lrun[a][b] = 0.f; }

  for (int kbk = 0; kbk < 7; kbk++){
    __syncthreads();
    {
      int jj = tid >> 3, c = (tid & 7)*8;
      int j = kbk*32 + jj;
      u32x4 kv = {0,0,0,0}, vv = {0,0,0,0};
      if (j < 197){
        int t = (j == 0) ? 0 : (1 + fi*196 + j - 1);
        kv = *(const u32x4*)(kg + (size_t)t*64 + c);
        vv = *(const u32x4*)(vg + (size_t)t*64 + c);
      }
      *(u32x4*)&Ks[jj][c] = kv;
      const u16* vp = (const u16*)&vv;
      #pragma unroll
      for (int i=0;i<8;i++) Vt[c+i][jj] = vp[i];
    }
    __syncthreads();

    s16x8 kf[2][2];
    #pragma unroll
    for (int nt=0; nt<2; nt++)
      #pragma unroll
      for (int kk=0; kk<2; kk++)
        kf[nt][kk] = ld16B(&Ks[nt*16 + l15][kk*32 + l4*8]);

    int key0 = kbk*32 + l15;
    bool bad0 = (key0 >= 197), bad1 = (key0 + 16 >= 197);

    #pragma unroll
    for (int mt=0; mt<4; mt++){
      f32x4 s0 = (f32x4){0.f,0.f,0.f,0.f}, s1 = (f32x4){0.f,0.f,0.f,0.f};
      s0 = mfma16(qf[mt][0], kf[0][0], s0);
      s0 = mfma16(qf[mt][1], kf[0][1], s0);
      s1 = mfma16(qf[mt][0], kf[1][0], s1);
      s1 = mfma16(qf[mt][1], kf[1][1], s1);
      #pragma unroll
      for (int r=0; r<4; r++){
        if (bad0) s0[r] = -1e30f;
        if (bad1) s1[r] = -1e30f;
      }
      #pragma unroll
      for (int r=0; r<4; r++){
        float mx = fmaxf(s0[r], s1[r]);
        mx = fmaxf(mx, __shfl_xor(mx, 1));
        mx = fmaxf(mx, __shfl_xor(mx, 2));
        mx = fmaxf(mx, __shfl_xor(mx, 4));
        mx = fmaxf(mx, __shfl_xor(mx, 8));
        float mold = mrun[mt][r];
        float mnew = fmaxf(mold, mx);
        float alpha = expf(mold - mnew);
        float p0 = expf(s0[r] - mnew);
        float p1 = expf(s1[r] - mnew);
        float rs = p0 + p1;
        rs += __shfl_xor(rs, 1);
        rs += __shfl_xor(rs, 2);
        rs += __shfl_xor(rs, 4);
        rs += __shfl_xor(rs, 8);
        lrun[mt][r] = lrun[mt][r]*alpha + rs;
        mrun[mt][r] = mnew;
        #pragma unroll
        for (int ntd=0; ntd<4; ntd++) acc[mt][ntd][r] *= alpha;
        int prow = mt*16 + l4*4 + r;
        Ps[w][prow][l15]      = f2bf(p0);
        Ps[w][prow][16 + l15] = f2bf(p1);
      }
    }

    s16x8 vf[4];
    #pragma unroll
    for (int ntd=0; ntd<4; ntd++) vf[ntd] = ld16B(&Vt[ntd*16 + l15][l4*8]);
    #pragma unroll
    for (int mt=0; mt<4; mt++){
      s16x8 pf = ld16B(&Ps[w][mt*16 + l15][l4*8]);
      #pragma unroll
      for (int ntd=0; ntd<4; ntd++)
        acc[mt][ntd] = mfma16(pf, vf[ntd], acc[mt][ntd]);
    }
  }

  u16* og = ob + ((size_t)bh*1569 + 1 + fi*196)*64;
  #pragma unroll
  for (int mt=0; mt<4; mt++){
    #pragma unroll
    for (int r=0; r<4; r++){
      int row = w*64 + mt*16 + l4*4 + r;
      if (row < 196){
        float inv = 1.f / lrun[mt][r];
        #pragma unroll
        for (int ntd=0; ntd<4; ntd++)
          og[(size_t)row*64 + ntd*16 + l15] = f2bf(acc[mt][ntd][r] * inv);
      }
    }
  }
}

// ---------------- out GEMM: gather(attn_out) [12552x768] @ [768x768] + bias -> f32 ----------------
__global__ __launch_bounds__(256) void gemm_out(const u16* __restrict__ AO, const u16* __restrict__ BT,
                                                const float* __restrict__ bias, float* __restrict__ C){
  __shared__ u16 As[128*64];
  __shared__ u16 Bs[128*64];
  const int M = 12552;
  const int NWG = 6*99;
  int logical = xcd_chunk(blockIdx.x, NWG);
  int bxi = logical % 6, byi = logical / 6;
  int bm = byi * 128, bn = bxi * 128;

  int tid = threadIdx.x;
  int w = tid >> 6, l = tid & 63, l15 = l & 15, l4 = l >> 4;
  int wr = w >> 1, wc = w & 1;
  f32x4 acc[4][4];
  #pragma unroll
  for (int a=0;a<4;a++)
    #pragma unroll
    for (int b=0;b<4;b++) acc[a][b] = (f32x4){0.f,0.f,0.f,0.f};

  int srow = l >> 3;
  int scol = (l & 7) * 8;

  for (int kt = 0; kt < 12; kt++){     // kt == head index (BK=64 == one head)
    #pragma unroll
    for (int p = 0; p < 4; p++){
      int i = w*4 + p;
      int row = i*8 + srow;
      int gr = bm + row; if (gr >= M) gr = M-1;
      int b = gr / 1569, t = gr - b*1569;
      gload16(AO + ((size_t)(b*12 + kt)*1569 + t)*64 + scol, &As[i*512]);
      gload16(BT + (size_t)(bn+row)*768 + kt*64 + scol, &Bs[i*512]);
    }
    __syncthreads();
    #pragma unroll
    for (int kk = 0; kk < 2; kk++){
      s16x8 af[4], bfr[4];
      #pragma unroll
      for (int mt=0; mt<4; mt++) af[mt]  = ld16B(&As[(wr*64 + mt*16 + l15)*64 + kk*32 + l4*8]);
      #pragma unroll
      for (int nt=0; nt<4; nt++) bfr[nt] = ld16B(&Bs[(wc*64 + nt*16 + l15)*64 + kk*32 + l4*8]);
      #pragma unroll
      for (int mt=0; mt<4; mt++)
        #pragma unroll
        for (int nt=0; nt<4; nt++)
          acc[mt][nt] = mfma16(af[mt], bfr[nt], acc[mt][nt]);
    }
    __syncthreads();
  }

  #pragma unroll
  for (int mt=0; mt<4; mt++){
    #pragma unroll
    for (int r=0; r<4; r++){
      int m = bm + wr*64 + mt*16 + l4*4 + r;
      if (m >= M) continue;
      #pragma unroll
      for (int nt=0; nt<4; nt++){
        int n = bn + wc*64 + nt*16 + l15;
        C[(size_t)m*768 + n] = acc[mt][nt][r] + bias[n];
      }
    }
  }
}

extern "C" void kernel_launch(void* const* d_in, const int* in_sizes, int n_in,
                              void* d_out, int out_size, void* d_ws, size_t ws_size,
                              hipStream_t stream){
  (void)in_sizes; (void)n_in; (void)out_size;
  const float* x    = (const float*)d_in[0];
  const float* Wqkv = (const float*)d_in[1];
  const float* Wout = (const float*)d_in[2];
  const float* bout = (const float*)d_in[3];
  float* out0 = (float*)d_out;
  float* out1 = out0 + (size_t)12552*768;   // cls_attn (96*1569)

  char* ws = (char*)d_ws;
  size_t off = 0;
  auto alloc = [&](size_t bytes)->char*{
    char* p = ws + off;
    off += (bytes + 255) & ~(size_t)255;
    return p;
  };
  u16* xb    = (u16*)alloc((size_t)12552*768*2);
  u16* wqkvT = (u16*)alloc((size_t)2304*768*2);
  u16* woutT = (u16*)alloc((size_t)768*768*2);
  u16* qb    = (u16*)alloc((size_t)96*1569*64*2);
  u16* kbuf  = (u16*)alloc((size_t)96*1569*64*2);
  u16* vbuf  = (u16*)alloc((size_t)96*1569*64*2);
  u16* ao    = (u16*)alloc((size_t)96*1569*64*2);
  float* simw = (float*)alloc((size_t)96*1569*4);
  float* bmax = (float*)alloc((size_t)96*8*4);
  float* pvp  = (float*)alloc((size_t)96*7*64*4);
  if (off > ws_size) return;   // workspace too small -> visible failure, no OOB writes

  k_cvt<<<2048, 256, 0, stream>>>(x, xb, 12552*768/4);
  k_transpose<<<dim3(72, 24), 256, 0, stream>>>(Wqkv, wqkvT, 768, 2304);
  k_transpose<<<dim3(24, 24), 256, 0, stream>>>(Wout, woutT, 768, 768);
  gemm_qkv<<<18*99, 256, 0, stream>>>(xb, wqkvT, qb, kbuf, vbuf);
  cls_sim<<<dim3(7, 96), 256, 0, stream>>>(qb, kbuf, simw, bmax);
  cls_fin<<<96, 256, 0, stream>>>(simw, bmax, out1);
  cls_pv<<<dim3(7, 96), 256, 0, stream>>>(out1, vbuf, pvp);
  cls_pv_red<<<96, 64, 0, stream>>>(pvp, ao);
  k_frame<<<768, 256, 0, stream>>>(qb, kbuf, vbuf, ao);
  gemm_out<<<6*99, 256, 0, stream>>>(ao, woutT, bout, out0);
}

// Round 4
// 214.296 us; speedup vs baseline: 1.6514x; 1.2651x over previous
//
#include <hip/hip_runtime.h>

typedef unsigned short u16;
typedef unsigned int u32;
typedef __attribute__((ext_vector_type(8))) short s16x8;   // 8 bf16 (4 VGPR) MFMA frag
typedef __attribute__((ext_vector_type(4))) float f32x4;
typedef __attribute__((ext_vector_type(4))) u32 u32x4;
typedef __attribute__((ext_vector_type(4))) float fvec4;

#define DEV static __device__ __forceinline__

typedef __attribute__((address_space(1))) unsigned char ga_u8;
typedef __attribute__((address_space(3))) unsigned char la_u8;

DEV u16 f2bf(float f){
  u32 u = __builtin_bit_cast(u32, f);
  u32 r = (u + 0x7FFFu + ((u >> 16) & 1u)) >> 16;
  return (u16)r;
}
DEV float bf2f(u16 v){
  u32 x = ((u32)v) << 16;
  return __builtin_bit_cast(float, x);
}
DEV f32x4 mfma16(s16x8 a, s16x8 b, f32x4 c){
  return __builtin_amdgcn_mfma_f32_16x16x32_bf16(a, b, c, 0, 0, 0);
}
DEV s16x8 ld16B(const u16* p){
  return __builtin_bit_cast(s16x8, *(const u32x4*)p);
}
// pack 2 f32 -> u32 of 2 bf16 (RNE); no builtin on gfx950, inline asm (T12)
DEV u32 cvt_pk_bf16(float lo, float hi){
  u32 r;
  asm volatile("v_cvt_pk_bf16_f32 %0, %1, %2" : "=v"(r) : "v"(lo), "v"(hi));
  return r;
}
// async global->LDS, 16B per lane; lds base must be wave-uniform, HW adds lane*16
DEV void gload16(const void* g, void* l){
  __builtin_amdgcn_global_load_lds((const ga_u8*)g, (la_u8*)l, 16, 0, 0);
}
// bijective XCD-chunked remap (m204)
DEV int xcd_chunk(int bid, int nwg){
  int q = nwg >> 3, r = nwg & 7;
  int xcd = bid & 7, lin = bid >> 3;
  return (xcd < r ? xcd*(q+1) : r*(q+1) + (xcd-r)*q) + lin;
}

// Problem sizes: B=8 NT=1569 DIM=768 H=12 D=64 BH=96 F=8 NQ=196 M=12552 Nqkv=2304 K=768

// ---------------- conversion kernels ----------------
__global__ __launch_bounds__(256) void k_cvt(const float* __restrict__ in, u16* __restrict__ out, int n4){
  int i = blockIdx.x*256 + threadIdx.x;
  int stride = gridDim.x*256;
  for (; i < n4; i += stride){
    fvec4 v = ((const fvec4*)in)[i];
    u16 o0 = f2bf(v[0]), o1 = f2bf(v[1]), o2 = f2bf(v[2]), o3 = f2bf(v[3]);
    u32 lo = (u32)o0 | ((u32)o1 << 16);
    u32 hi = (u32)o2 | ((u32)o3 << 16);
    ((u32*)out)[2*i]   = lo;
    ((u32*)out)[2*i+1] = hi;
  }
}

// W[K][N] f32 -> WT[N][K] bf16, LDS-tiled: coalesced reads AND writes.
__global__ __launch_bounds__(256) void k_transpose(const float* __restrict__ W, u16* __restrict__ WT, int K, int N){
  __shared__ float tile[32][33];
  int bn = blockIdx.x * 32;
  int bk = blockIdx.y * 32;
  int tx = threadIdx.x & 31, ty = threadIdx.x >> 5;
  #pragma unroll
  for (int r = ty; r < 32; r += 8)
    tile[r][tx] = W[(size_t)(bk + r)*N + bn + tx];
  __syncthreads();
  #pragma unroll
  for (int r = ty; r < 32; r += 8)
    WT[(size_t)(bn + r)*K + bk + tx] = f2bf(tile[tx][r]);
}

// ---------------- QKV GEMM: [12552x768] @ [768x2304] -> scatter q,k,v (bh,t,d) bf16 ----------------
__global__ __launch_bounds__(256) void gemm_qkv(const u16* __restrict__ A, const u16* __restrict__ BT,
                                                u16* __restrict__ qout, u16* __restrict__ kout, u16* __restrict__ vout){
  __shared__ u16 As[128*64];
  __shared__ u16 Bs[128*64];
  const int M = 12552;
  const int NWG = 18*99;
  int logical = xcd_chunk(blockIdx.x, NWG);
  int bxi = logical % 18, byi = logical / 18;
  int bm = byi * 128, bn = bxi * 128;

  int tid = threadIdx.x;
  int w = tid >> 6, l = tid & 63, l15 = l & 15, l4 = l >> 4;
  int wr = w >> 1, wc = w & 1;
  f32x4 acc[4][4];
  #pragma unroll
  for (int a=0;a<4;a++)
    #pragma unroll
    for (int b=0;b<4;b++) acc[a][b] = (f32x4){0.f,0.f,0.f,0.f};

  int srow = l >> 3;
  int scol = (l & 7) * 8;

  for (int kt = 0; kt < 12; kt++){
    #pragma unroll
    for (int p = 0; p < 4; p++){
      int i = w*4 + p;
      int row = i*8 + srow;
      int gr = bm + row; if (gr >= M) gr = M-1;
      gload16(A  + (size_t)gr*768        + kt*64 + scol, &As[i*512]);
      gload16(BT + (size_t)(bn+row)*768  + kt*64 + scol, &Bs[i*512]);
    }
    __syncthreads();
    #pragma unroll
    for (int kk = 0; kk < 2; kk++){
      s16x8 af[4], bfr[4];
      #pragma unroll
      for (int mt=0; mt<4; mt++) af[mt]  = ld16B(&As[(wr*64 + mt*16 + l15)*64 + kk*32 + l4*8]);
      #pragma unroll
      for (int nt=0; nt<4; nt++) bfr[nt] = ld16B(&Bs[(wc*64 + nt*16 + l15)*64 + kk*32 + l4*8]);
      #pragma unroll
      for (int mt=0; mt<4; mt++)
        #pragma unroll
        for (int nt=0; nt<4; nt++)
          acc[mt][nt] = mfma16(af[mt], bfr[nt], acc[mt][nt]);
    }
    __syncthreads();
  }

  int which = bn / 768;
  int col0  = bn - which*768 + wc*64;
  int h     = col0 >> 6;
  u16* dst  = (which==0) ? qout : ((which==1) ? kout : vout);
  float scale = (which==0) ? 0.125f : 1.f;
  #pragma unroll
  for (int mt=0; mt<4; mt++){
    #pragma unroll
    for (int r=0; r<4; r++){
      int m = bm + wr*64 + mt*16 + l4*4 + r;
      if (m >= M) continue;
      int b = m / 1569, t = m - b*1569;
      u16* drow = dst + ((size_t)(b*12 + h)*1569 + t)*64 + l15;
      #pragma unroll
      for (int nt=0; nt<4; nt++)
        drow[nt*16] = f2bf(acc[mt][nt][r] * scale);
    }
  }
}

// ---------------- CLS attention, parallelized ----------------
__global__ __launch_bounds__(256) void cls_sim(const u16* __restrict__ qb, const u16* __restrict__ kb,
                                               float* __restrict__ sim, float* __restrict__ bmax){
  int c = blockIdx.x, g = blockIdx.y;
  int tid = threadIdx.x;
  __shared__ float qv[64];
  __shared__ float red[256];
  if (tid < 64) qv[tid] = bf2f(qb[(size_t)g*1569*64 + tid]);
  __syncthreads();
  int j = c*256 + tid;
  float s = -1e30f;
  if (j < 1569){
    const u16* kr = kb + ((size_t)g*1569 + j)*64;
    float a = 0.f;
    #pragma unroll
    for (int d0 = 0; d0 < 64; d0 += 8){
      u32x4 u = *(const u32x4*)(kr + d0);
      const u16* us = (const u16*)&u;
      #pragma unroll
      for (int i=0;i<8;i++) a += qv[d0+i]*bf2f(us[i]);
    }
    s = a;
    sim[(size_t)g*1569 + j] = s;
  }
  red[tid] = s; __syncthreads();
  for (int st=128; st>0; st>>=1){ if (tid<st) red[tid] = fmaxf(red[tid], red[tid+st]); __syncthreads(); }
  if (tid == 0) bmax[g*8 + c] = red[0];
}

__global__ __launch_bounds__(256) void cls_fin(float* __restrict__ sim, const float* __restrict__ bmax,
                                               float* __restrict__ attn){
  int g = blockIdx.x, tid = threadIdx.x;
  __shared__ float red[256];
  float m = -1e30f;
  #pragma unroll
  for (int c=0;c<7;c++) m = fmaxf(m, bmax[g*8+c]);
  float ls = 0.f;
  for (int j = tid; j < 1569; j += 256){
    float e = expf(sim[(size_t)g*1569+j] - m);
    sim[(size_t)g*1569+j] = e;
    ls += e;
  }
  red[tid] = ls; __syncthreads();
  for (int st=128; st>0; st>>=1){ if (tid<st) red[tid] += red[tid+st]; __syncthreads(); }
  float inv = 1.f/red[0];
  for (int j = tid; j < 1569; j += 256)
    attn[(size_t)g*1569+j] = sim[(size_t)g*1569+j]*inv;
}

__global__ __launch_bounds__(256) void cls_pv(const float* __restrict__ attn, const u16* __restrict__ vb,
                                              float* __restrict__ pvp){
  int c = blockIdx.x, g = blockIdx.y;
  int tid = threadIdx.x;
  int d = tid & 63, kk = tid >> 6;
  __shared__ float red[256];
  float a = 0.f;
  for (int jj = kk; jj < 256; jj += 4){
    int j = c*256 + jj;
    if (j < 1569) a += attn[(size_t)g*1569+j] * bf2f(vb[((size_t)g*1569+j)*64 + d]);
  }
  red[tid] = a; __syncthreads();
  if (tid < 64) pvp[((size_t)g*7 + c)*64 + tid] = red[tid]+red[tid+64]+red[tid+128]+red[tid+192];
}

__global__ __launch_bounds__(64) void cls_pv_red(const float* __restrict__ pvp, u16* __restrict__ ob){
  int g = blockIdx.x, d = threadIdx.x;
  float s = 0.f;
  #pragma unroll
  for (int c=0;c<7;c++) s += pvp[((size_t)g*7+c)*64 + d];
  ob[(size_t)g*1569*64 + d] = f2bf(s);
}

// ---------------- frame attention v2: full-KV-in-LDS, fixed-shift softmax ----------------
// 768 blocks (one per (bh,frame)), 4 waves x 64 q-rows. K,V staged ONCE; no barriers
// in the key loop; p = exp(s-8) (constant shift cancels exactly in normalization);
// row-sum reduced once at the end. P packed as u32 pairs; V columns interleaved
// (j, j+16) -> (2j, 2j+1) so P/V k-slot orders match (dot product is k-permutation
// invariant).
__global__ __launch_bounds__(256) void k_frame(const u16* __restrict__ qb, const u16* __restrict__ kb,
                                               const u16* __restrict__ vb, u16* __restrict__ ob){
  int g = blockIdx.x;
  int bh = g >> 3, fi = g & 7;
  int tid = threadIdx.x;
  int w = tid >> 6, l = tid & 63;
  int l15 = l & 15, l4 = l >> 4;

  __shared__ u16 Ks[208][72];      // keys 0..207 (197..207 zeroed), stride 144B -> 2-way max
  __shared__ u16 Vt[64][232];      // [d][key-slot], cols>=197-slot zeroed, stride 464B
  __shared__ u16 Ps[4][64][40];    // per-wave P [qrow][key-slot 0..31], stride 80B

  const u16* qg = qb + ((size_t)bh*1569 + 1 + fi*196)*64;
  const u16* kg = kb + (size_t)bh*1569*64;
  const u16* vg = vb + (size_t)bh*1569*64;

  // ---- stage K + V (once) ----
  {
    int jj = tid >> 3, c = (tid & 7)*8;     // jj 0..31, c 0..56
    #pragma unroll
    for (int base = 0; base < 224; base += 32){
      int j = base + jj;
      u32x4 kv = {0,0,0,0}, vv = {0,0,0,0};
      if (j < 197){
        int t = (j == 0) ? 0 : (1 + fi*196 + j - 1);
        kv = *(const u32x4*)(kg + (size_t)t*64 + c);
        vv = *(const u32x4*)(vg + (size_t)t*64 + c);
      }
      if (j < 208) *(u32x4*)&Ks[j][c] = kv;
      int jl = j & 31;
      int col = (j & ~31) + ((jl & 15)*2 + (jl >> 4));   // slot interleave
      const u16* vp = (const u16*)&vv;
      #pragma unroll
      for (int i=0;i<8;i++) Vt[c+i][col] = vp[i];
    }
  }

  // ---- Q fragments (rows w*64..w*64+63, masked >=196) ----
  s16x8 qf[4][2];
  #pragma unroll
  for (int mt=0; mt<4; mt++){
    int row = w*64 + mt*16 + l15;
    #pragma unroll
    for (int kk=0; kk<2; kk++){
      if (row < 196) qf[mt][kk] = ld16B(qg + (size_t)row*64 + kk*32 + l4*8);
      else { u32x4 z = {0,0,0,0}; qf[mt][kk] = __builtin_bit_cast(s16x8, z); }
    }
  }

  f32x4 acc[4][4];
  float rsum[4][4];
  #pragma unroll
  for (int a=0;a<4;a++)
    #pragma unroll
    for (int b=0;b<4;b++){ acc[a][b] = (f32x4){0.f,0.f,0.f,0.f}; rsum[a][b] = 0.f; }

  __syncthreads();   // staging complete (the only block-wide barrier)

  for (int ck = 0; ck < 7; ck++){
    // K fragments for this 32-key chunk; clamp tail rows into the zeroed region
    int r0 = ck*32 + l15;
    int r1 = r0 + 16; if (r1 > 207) r1 = 207;   // zeroed rows -> s=0 -> masked p=0
    s16x8 kf0[2], kf1[2];
    #pragma unroll
    for (int kk=0; kk<2; kk++){
      kf0[kk] = ld16B(&Ks[r0][kk*32 + l4*8]);
      kf1[kk] = ld16B(&Ks[r1][kk*32 + l4*8]);
    }
    bool ok0 = (ck*32 + l15) < 197;
    bool ok1 = (ck*32 + 16 + l15) < 197;

    #pragma unroll
    for (int mt=0; mt<4; mt++){
      __builtin_amdgcn_s_setprio(1);
      f32x4 s0 = (f32x4){0.f,0.f,0.f,0.f}, s1 = (f32x4){0.f,0.f,0.f,0.f};
      s0 = mfma16(qf[mt][0], kf0[0], s0);
      s0 = mfma16(qf[mt][1], kf0[1], s0);
      s1 = mfma16(qf[mt][0], kf1[0], s1);
      s1 = mfma16(qf[mt][1], kf1[1], s1);
      __builtin_amdgcn_s_setprio(0);
      #pragma unroll
      for (int r=0; r<4; r++){
        float p0 = ok0 ? __expf(s0[r] - 8.f) : 0.f;
        float p1 = ok1 ? __expf(s1[r] - 8.f) : 0.f;
        rsum[mt][r] += p0 + p1;
        int prow = mt*16 + l4*4 + r;
        *(u32*)&Ps[w][prow][2*l15] = cvt_pk_bf16(p0, p1);   // slots (2*l15, 2*l15+1)
      }
    }

    // PV for this chunk (per-wave P buffer: compiler inserts lgkmcnt, no barrier)
    s16x8 vf[4];
    #pragma unroll
    for (int ntd=0; ntd<4; ntd++) vf[ntd] = ld16B(&Vt[ntd*16 + l15][ck*32 + l4*8]);
    #pragma unroll
    for (int mt=0; mt<4; mt++){
      s16x8 pf = ld16B(&Ps[w][mt*16 + l15][l4*8]);
      __builtin_amdgcn_s_setprio(1);
      #pragma unroll
      for (int ntd=0; ntd<4; ntd++)
        acc[mt][ntd] = mfma16(pf, vf[ntd], acc[mt][ntd]);
      __builtin_amdgcn_s_setprio(0);
    }
  }

  // ---- final row-sum reduce (once) + store ----
  u16* og = ob + ((size_t)bh*1569 + 1 + fi*196)*64;
  #pragma unroll
  for (int mt=0; mt<4; mt++){
    #pragma unroll
    for (int r=0; r<4; r++){
      float rs = rsum[mt][r];
      rs += __shfl_xor(rs, 1);
      rs += __shfl_xor(rs, 2);
      rs += __shfl_xor(rs, 4);
      rs += __shfl_xor(rs, 8);
      int row = w*64 + mt*16 + l4*4 + r;
      if (row < 196){
        float inv = 1.f / rs;
        #pragma unroll
        for (int ntd=0; ntd<4; ntd++)
          og[(size_t)row*64 + ntd*16 + l15] = f2bf(acc[mt][ntd][r] * inv);
      }
    }
  }
}

// ---------------- out GEMM: gather(attn_out) [12552x768] @ [768x768] + bias -> f32 ----------------
__global__ __launch_bounds__(256) void gemm_out(const u16* __restrict__ AO, const u16* __restrict__ BT,
                                                const float* __restrict__ bias, float* __restrict__ C){
  __shared__ u16 As[128*64];
  __shared__ u16 Bs[128*64];
  const int M = 12552;
  const int NWG = 6*99;
  int logical = xcd_chunk(blockIdx.x, NWG);
  int bxi = logical % 6, byi = logical / 6;
  int bm = byi * 128, bn = bxi * 128;

  int tid = threadIdx.x;
  int w = tid >> 6, l = tid & 63, l15 = l & 15, l4 = l >> 4;
  int wr = w >> 1, wc = w & 1;
  f32x4 acc[4][4];
  #pragma unroll
  for (int a=0;a<4;a++)
    #pragma unroll
    for (int b=0;b<4;b++) acc[a][b] = (f32x4){0.f,0.f,0.f,0.f};

  int srow = l >> 3;
  int scol = (l & 7) * 8;

  for (int kt = 0; kt < 12; kt++){
    #pragma unroll
    for (int p = 0; p < 4; p++){
      int i = w*4 + p;
      int row = i*8 + srow;
      int gr = bm + row; if (gr >= M) gr = M-1;
      int b = gr / 1569, t = gr - b*1569;
      gload16(AO + ((size_t)(b*12 + kt)*1569 + t)*64 + scol, &As[i*512]);
      gload16(BT + (size_t)(bn+row)*768 + kt*64 + scol, &Bs[i*512]);
    }
    __syncthreads();
    #pragma unroll
    for (int kk = 0; kk < 2; kk++){
      s16x8 af[4], bfr[4];
      #pragma unroll
      for (int mt=0; mt<4; mt++) af[mt]  = ld16B(&As[(wr*64 + mt*16 + l15)*64 + kk*32 + l4*8]);
      #pragma unroll
      for (int nt=0; nt<4; nt++) bfr[nt] = ld16B(&Bs[(wc*64 + nt*16 + l15)*64 + kk*32 + l4*8]);
      #pragma unroll
      for (int mt=0; mt<4; mt++)
        #pragma unroll
        for (int nt=0; nt<4; nt++)
          acc[mt][nt] = mfma16(af[mt], bfr[nt], acc[mt][nt]);
    }
    __syncthreads();
  }

  #pragma unroll
  for (int mt=0; mt<4; mt++){
    #pragma unroll
    for (int r=0; r<4; r++){
      int m = bm + wr*64 + mt*16 + l4*4 + r;
      if (m >= M) continue;
      #pragma unroll
      for (int nt=0; nt<4; nt++){
        int n = bn + wc*64 + nt*16 + l15;
        C[(size_t)m*768 + n] = acc[mt][nt][r] + bias[n];
      }
    }
  }
}

extern "C" void kernel_launch(void* const* d_in, const int* in_sizes, int n_in,
                              void* d_out, int out_size, void* d_ws, size_t ws_size,
                              hipStream_t stream){
  (void)in_sizes; (void)n_in; (void)out_size;
  const float* x    = (const float*)d_in[0];
  const float* Wqkv = (const float*)d_in[1];
  const float* Wout = (const float*)d_in[2];
  const float* bout = (const float*)d_in[3];
  float* out0 = (float*)d_out;
  float* out1 = out0 + (size_t)12552*768;   // cls_attn (96*1569)

  char* ws = (char*)d_ws;
  size_t off = 0;
  auto alloc = [&](size_t bytes)->char*{
    char* p = ws + off;
    off += (bytes + 255) & ~(size_t)255;
    return p;
  };
  u16* xb    = (u16*)alloc((size_t)12552*768*2);
  u16* wqkvT = (u16*)alloc((size_t)2304*768*2);
  u16* woutT = (u16*)alloc((size_t)768*768*2);
  u16* qb    = (u16*)alloc((size_t)96*1569*64*2);
  u16* kbuf  = (u16*)alloc((size_t)96*1569*64*2);
  u16* vbuf  = (u16*)alloc((size_t)96*1569*64*2);
  u16* ao    = (u16*)alloc((size_t)96*1569*64*2);
  float* simw = (float*)alloc((size_t)96*1569*4);
  float* bmax = (float*)alloc((size_t)96*8*4);
  float* pvp  = (float*)alloc((size_t)96*7*64*4);
  if (off > ws_size) return;

  k_cvt<<<2048, 256, 0, stream>>>(x, xb, 12552*768/4);
  k_transpose<<<dim3(72, 24), 256, 0, stream>>>(Wqkv, wqkvT, 768, 2304);
  k_transpose<<<dim3(24, 24), 256, 0, stream>>>(Wout, woutT, 768, 768);
  gemm_qkv<<<18*99, 256, 0, stream>>>(xb, wqkvT, qb, kbuf, vbuf);
  cls_sim<<<dim3(7, 96), 256, 0, stream>>>(qb, kbuf, simw, bmax);
  cls_fin<<<96, 256, 0, stream>>>(simw, bmax, out1);
  cls_pv<<<dim3(7, 96), 256, 0, stream>>>(out1, vbuf, pvp);
  cls_pv_red<<<96, 64, 0, stream>>>(pvp, ao);
  k_frame<<<768, 256, 0, stream>>>(qb, kbuf, vbuf, ao);
  gemm_out<<<6*99, 256, 0, stream>>>(ao, woutT, bout, out0);
}

// Round 5
// 193.887 us; speedup vs baseline: 1.8252x; 1.1053x over previous
//
#include <hip/hip_runtime.h>

typedef unsigned short u16;
typedef unsigned int u32;
typedef __attribute__((ext_vector_type(8))) short s16x8;   // 8 bf16 (4 VGPR) MFMA frag
typedef __attribute__((ext_vector_type(4))) float f32x4;
typedef __attribute__((ext_vector_type(4))) u32 u32x4;
typedef __attribute__((ext_vector_type(4))) float fvec4;

#define DEV static __device__ __forceinline__

typedef __attribute__((address_space(1))) unsigned char ga_u8;
typedef __attribute__((address_space(3))) unsigned char la_u8;

DEV u16 f2bf(float f){
  u32 u = __builtin_bit_cast(u32, f);
  u32 r = (u + 0x7FFFu + ((u >> 16) & 1u)) >> 16;
  return (u16)r;
}
DEV float bf2f(u16 v){
  u32 x = ((u32)v) << 16;
  return __builtin_bit_cast(float, x);
}
DEV f32x4 mfma16(s16x8 a, s16x8 b, f32x4 c){
  return __builtin_amdgcn_mfma_f32_16x16x32_bf16(a, b, c, 0, 0, 0);
}
DEV s16x8 ld16B(const u16* p){
  return __builtin_bit_cast(s16x8, *(const u32x4*)p);
}
DEV u32 cvt_pk_bf16(float lo, float hi){
  u32 r;
  asm volatile("v_cvt_pk_bf16_f32 %0, %1, %2" : "=v"(r) : "v"(lo), "v"(hi));
  return r;
}
DEV void gload16(const void* g, void* l){
  __builtin_amdgcn_global_load_lds((const ga_u8*)g, (la_u8*)l, 16, 0, 0);
}
DEV int xcd_chunk(int bid, int nwg){
  int q = nwg >> 3, r = nwg & 7;
  int xcd = bid & 7, lin = bid >> 3;
  return (xcd < r ? xcd*(q+1) : r*(q+1) + (xcd-r)*q) + lin;
}

#define BARRIER() __builtin_amdgcn_s_barrier()
#define LGKM0()   asm volatile("s_waitcnt lgkmcnt(0)" ::: "memory")
#define VMC4()    asm volatile("s_waitcnt vmcnt(4)" ::: "memory")
#define VMC0()    asm volatile("s_waitcnt vmcnt(0)" ::: "memory")

// Problem sizes: B=8 NT=1569 DIM=768 H=12 D=64 BH=96 F=8 NQ=196 M=12552 Nqkv=2304 K=768

// ---------------- conversion kernels ----------------
__global__ __launch_bounds__(256) void k_cvt(const float* __restrict__ in, u16* __restrict__ out, int n4){
  int i = blockIdx.x*256 + threadIdx.x;
  int stride = gridDim.x*256;
  for (; i < n4; i += stride){
    fvec4 v = ((const fvec4*)in)[i];
    u16 o0 = f2bf(v[0]), o1 = f2bf(v[1]), o2 = f2bf(v[2]), o3 = f2bf(v[3]);
    u32 lo = (u32)o0 | ((u32)o1 << 16);
    u32 hi = (u32)o2 | ((u32)o3 << 16);
    ((u32*)out)[2*i]   = lo;
    ((u32*)out)[2*i+1] = hi;
  }
}

// W[K][N] f32 -> WT[N][K] bf16, LDS-tiled
__global__ __launch_bounds__(256) void k_transpose(const float* __restrict__ W, u16* __restrict__ WT, int K, int N){
  __shared__ float tile[32][33];
  int bn = blockIdx.x * 32;
  int bk = blockIdx.y * 32;
  int tx = threadIdx.x & 31, ty = threadIdx.x >> 5;
  #pragma unroll
  for (int r = ty; r < 32; r += 8)
    tile[r][tx] = W[(size_t)(bk + r)*N + bn + tx];
  __syncthreads();
  #pragma unroll
  for (int r = ty; r < 32; r += 8)
    WT[(size_t)(bn + r)*K + bk + tx] = f2bf(tile[tx][r]);
}

// ---------------- QKV GEMM, 256x256 8-phase schedule (T1+T2+T3+T4+T5) ----------------
// [12552x768] @ [768x2304] -> scatter q,k,v (bh,t,d) bf16.
// 8 waves (2M x 4N), per-wave C = 128x64 (acc[8][4]). BK=64, 12 K-tiles, dbuf = kt&1.
// LDS: [dbuf][half][128][64] for A and B = 128 KB. Staging via global_load_lds
// (linear dest) with row-XOR pre-swizzled SOURCE; ds_read applies the same XOR
// (involution, both-sides rule #21). Counted vmcnt(4) at phases 4/8 only.
// Stage timeline (iter i computes kt0=2i dbuf0 [ph1-4], kt1=2i+1 dbuf1 [ph5-8]):
//   ph1: B0(kt1)  ph2: B1(kt1)  ph3: A0(kt0+2) ph4: A1(kt0+2) [vmcnt4]
//   ph5: B0(kt0+2) ph6: B1(kt0+2) ph7: A0(kt1+2) ph8: A1(kt1+2) [vmcnt4]
// Safety: a buffer-half is staged only in a phase after the barrier that follows
// its last ds_read (dbuf reads all issued+drained by ph2/ph6's lgkmcnt+barrier).
__global__ __launch_bounds__(512, 2) void gemm_qkv(const u16* __restrict__ A, const u16* __restrict__ BT,
                                                   u16* __restrict__ qout, u16* __restrict__ kout, u16* __restrict__ vout){
  __shared__ u16 sA[2][2][128*64];
  __shared__ u16 sB[2][2][128*64];
  const int M = 12552;
  const int NWG = 50*9;
  int logical = xcd_chunk(blockIdx.x, NWG);
  int bxi = logical % 9, byi = logical / 9;   // n-fastest within XCD chunk
  int bm = byi * 256, bn = bxi * 256;

  int tid = threadIdx.x;
  int w = tid >> 6, l = tid & 63, l15 = l & 15, l4 = l >> 4;
  int wm = w >> 2, wn = w & 3;
  int swz = (l15 & 7) << 3;     // element-level read swizzle (== byte (row&7)<<4)

  f32x4 acc[8][4];
  #pragma unroll
  for (int a=0;a<8;a++)
    #pragma unroll
    for (int b=0;b<4;b++) acc[a][b] = (f32x4){0.f,0.f,0.f,0.f};

  // ---- staging helpers: 1 half-tile = 1024 x 16B chunks = 2 issues of 512 threads
  auto stageA = [&](int dbuf, int h, int kt){
    #pragma unroll
    for (int i=0;i<2;i++){
      int ci = i*512 + tid;
      int cs = ci ^ ((ci>>3)&7);              // inverse(=same) swizzle on SOURCE
      int r = cs>>3, cc = (cs&7)*8;
      int gr = bm + h*128 + r; if (gr >= M) gr = M-1;   // clamp, junk rows never stored
      gload16(A + (size_t)gr*768 + kt*64 + cc, &sA[dbuf][h][(i*512 + (w<<6))*8]);
    }
  };
  auto stageB = [&](int dbuf, int h, int kt){
    #pragma unroll
    for (int i=0;i<2;i++){
      int ci = i*512 + tid;
      int cs = ci ^ ((ci>>3)&7);
      int r = cs>>3, cc = (cs&7)*8;
      gload16(BT + (size_t)(bn + h*128 + r)*768 + kt*64 + cc, &sB[dbuf][h][(i*512 + (w<<6))*8]);
    }
  };

  s16x8 af[4][2], bf[4][2];
  // frag loads (swizzled read side)
  #define LDA_(d, mi, kk) ld16B(&sA[d][wm][(((mi)*16 + l15)*64 + (kk)*32 + l4*8) ^ swz])
  #define LDB_(d, ni, kk) ld16B(&sB[d][(wn*64 + (ni)*16 + l15)>>7][((((wn*64 + (ni)*16 + l15)&127))*64 + (kk)*32 + l4*8) ^ swz])
  #define QUAD(MH, NH) do{ \
    __builtin_amdgcn_s_setprio(1); \
    _Pragma("unroll") \
    for (int j=0;j<4;j++){ \
      _Pragma("unroll") \
      for (int n=0;n<2;n++){ \
        acc[(MH)*4+j][(NH)*2+n] = mfma16(af[j][0], bf[(NH)*2+n][0], acc[(MH)*4+j][(NH)*2+n]); \
        acc[(MH)*4+j][(NH)*2+n] = mfma16(af[j][1], bf[(NH)*2+n][1], acc[(MH)*4+j][(NH)*2+n]); \
      } } \
    __builtin_amdgcn_s_setprio(0); }while(0)

  // ---- prologue: kt0 full + kt1 A-halves; leave A(kt1) in flight (vmcnt 4)
  stageA(0,0,0); stageA(0,1,0); stageB(0,0,0); stageB(0,1,0);
  stageA(1,0,1); stageA(1,1,1);
  VMC4();
  BARRIER();

  #pragma unroll 1
  for (int it = 0; it < 6; ++it){
    int kt1 = 2*it + 1;
    bool full = (it < 5);
    // ---------- phase 1: quad(0,0) of dbuf0 ----------
    #pragma unroll
    for (int j=0;j<4;j++){ af[j][0]=LDA_(0,j,0); af[j][1]=LDA_(0,j,1); }
    #pragma unroll
    for (int n=0;n<2;n++){ bf[n][0]=LDB_(0,n,0); bf[n][1]=LDB_(0,n,1); }
    stageB(1, 0, kt1);
    BARRIER(); LGKM0();
    QUAD(0,0);
    BARRIER();
    // ---------- phase 2: quad(0,1) ----------
    #pragma unroll
    for (int n=2;n<4;n++){ bf[n][0]=LDB_(0,n,0); bf[n][1]=LDB_(0,n,1); }
    stageB(1, 1, kt1);
    BARRIER(); LGKM0();
    QUAD(0,1);
    BARRIER();
    // ---------- phase 3: quad(1,0) ----------
    #pragma unroll
    for (int j=0;j<4;j++){ af[j][0]=LDA_(0,4+j,0); af[j][1]=LDA_(0,4+j,1); }
    if (full) stageA(0, 0, kt1+1);
    BARRIER(); LGKM0();
    QUAD(1,0);
    BARRIER();
    // ---------- phase 4: quad(1,1) ----------
    if (full) stageA(0, 1, kt1+1);
    BARRIER();
    QUAD(1,1);
    if (full) { VMC4(); } else { VMC0(); }
    BARRIER();
    // ---------- phase 5: quad(0,0) of dbuf1 ----------
    #pragma unroll
    for (int j=0;j<4;j++){ af[j][0]=LDA_(1,j,0); af[j][1]=LDA_(1,j,1); }
    #pragma unroll
    for (int n=0;n<2;n++){ bf[n][0]=LDB_(1,n,0); bf[n][1]=LDB_(1,n,1); }
    if (full) stageB(0, 0, kt1+1);
    BARRIER(); LGKM0();
    QUAD(0,0);
    BARRIER();
    // ---------- phase 6: quad(0,1) ----------
    #pragma unroll
    for (int n=2;n<4;n++){ bf[n][0]=LDB_(1,n,0); bf[n][1]=LDB_(1,n,1); }
    if (full) stageB(0, 1, kt1+1);
    BARRIER(); LGKM0();
    QUAD(0,1);
    BARRIER();
    // ---------- phase 7: quad(1,0) ----------
    #pragma unroll
    for (int j=0;j<4;j++){ af[j][0]=LDA_(1,4+j,0); af[j][1]=LDA_(1,4+j,1); }
    if (full) stageA(1, 0, kt1+2);
    BARRIER(); LGKM0();
    QUAD(1,0);
    BARRIER();
    // ---------- phase 8: quad(1,1) ----------
    if (full) stageA(1, 1, kt1+2);
    BARRIER();
    QUAD(1,1);
    if (full) VMC4();
    BARRIER();
  }
  #undef LDA_
  #undef LDB_
  #undef QUAD

  // ---- epilogue: scatter to q/k/v. 256-tile never straddles q/k/v (768=3*256)
  // or head boundaries; head constant per wave.
  int which = bn / 768;
  int h = ((bn - which*768) >> 6) + wn;
  u16* dst  = (which==0) ? qout : ((which==1) ? kout : vout);
  float scale = (which==0) ? 0.125f : 1.f;
  #pragma unroll
  for (int mi=0; mi<8; mi++){
    #pragma unroll
    for (int r=0; r<4; r++){
      int m = bm + wm*128 + mi*16 + l4*4 + r;
      if (m >= M) continue;
      int b = m / 1569, t = m - b*1569;
      u16* drow = dst + ((size_t)(b*12 + h)*1569 + t)*64 + l15;
      #pragma unroll
      for (int n=0; n<4; n++)
        drow[n*16] = f2bf(acc[mi][n][r] * scale);
    }
  }
}

// ---------------- CLS attention, parallelized ----------------
__global__ __launch_bounds__(256) void cls_sim(const u16* __restrict__ qb, const u16* __restrict__ kb,
                                               float* __restrict__ sim, float* __restrict__ bmax){
  int c = blockIdx.x, g = blockIdx.y;
  int tid = threadIdx.x;
  __shared__ float qv[64];
  __shared__ float red[256];
  if (tid < 64) qv[tid] = bf2f(qb[(size_t)g*1569*64 + tid]);
  __syncthreads();
  int j = c*256 + tid;
  float s = -1e30f;
  if (j < 1569){
    const u16* kr = kb + ((size_t)g*1569 + j)*64;
    float a = 0.f;
    #pragma unroll
    for (int d0 = 0; d0 < 64; d0 += 8){
      u32x4 u = *(const u32x4*)(kr + d0);
      const u16* us = (const u16*)&u;
      #pragma unroll
      for (int i=0;i<8;i++) a += qv[d0+i]*bf2f(us[i]);
    }
    s = a;
    sim[(size_t)g*1569 + j] = s;
  }
  red[tid] = s; __syncthreads();
  for (int st=128; st>0; st>>=1){ if (tid<st) red[tid] = fmaxf(red[tid], red[tid+st]); __syncthreads(); }
  if (tid == 0) bmax[g*8 + c] = red[0];
}

__global__ __launch_bounds__(256) void cls_fin(float* __restrict__ sim, const float* __restrict__ bmax,
                                               float* __restrict__ attn){
  int g = blockIdx.x, tid = threadIdx.x;
  __shared__ float red[256];
  float m = -1e30f;
  #pragma unroll
  for (int c=0;c<7;c++) m = fmaxf(m, bmax[g*8+c]);
  float ls = 0.f;
  for (int j = tid; j < 1569; j += 256){
    float e = expf(sim[(size_t)g*1569+j] - m);
    sim[(size_t)g*1569+j] = e;
    ls += e;
  }
  red[tid] = ls; __syncthreads();
  for (int st=128; st>0; st>>=1){ if (tid<st) red[tid] += red[tid+st]; __syncthreads(); }
  float inv = 1.f/red[0];
  for (int j = tid; j < 1569; j += 256)
    attn[(size_t)g*1569+j] = sim[(size_t)g*1569+j]*inv;
}

__global__ __launch_bounds__(256) void cls_pv(const float* __restrict__ attn, const u16* __restrict__ vb,
                                              float* __restrict__ pvp){
  int c = blockIdx.x, g = blockIdx.y;
  int tid = threadIdx.x;
  int d = tid & 63, kk = tid >> 6;
  __shared__ float red[256];
  float a = 0.f;
  for (int jj = kk; jj < 256; jj += 4){
    int j = c*256 + jj;
    if (j < 1569) a += attn[(size_t)g*1569+j] * bf2f(vb[((size_t)g*1569+j)*64 + d]);
  }
  red[tid] = a; __syncthreads();
  if (tid < 64) pvp[((size_t)g*7 + c)*64 + tid] = red[tid]+red[tid+64]+red[tid+128]+red[tid+192];
}

__global__ __launch_bounds__(64) void cls_pv_red(const float* __restrict__ pvp, u16* __restrict__ ob){
  int g = blockIdx.x, d = threadIdx.x;
  float s = 0.f;
  #pragma unroll
  for (int c=0;c<7;c++) s += pvp[((size_t)g*7+c)*64 + d];
  ob[(size_t)g*1569*64 + d] = f2bf(s);
}

// ---------------- frame attention: full-KV-in-LDS, fixed-shift softmax ----------------
__global__ __launch_bounds__(256) void k_frame(const u16* __restrict__ qb, const u16* __restrict__ kb,
                                               const u16* __restrict__ vb, u16* __restrict__ ob){
  int g = blockIdx.x;
  int bh = g >> 3, fi = g & 7;
  int tid = threadIdx.x;
  int w = tid >> 6, l = tid & 63;
  int l15 = l & 15, l4 = l >> 4;

  __shared__ u16 Ks[208][72];
  __shared__ u16 Vt[64][232];
  __shared__ u16 Ps[4][64][40];

  const u16* qg = qb + ((size_t)bh*1569 + 1 + fi*196)*64;
  const u16* kg = kb + (size_t)bh*1569*64;
  const u16* vg = vb + (size_t)bh*1569*64;

  {
    int jj = tid >> 3, c = (tid & 7)*8;
    #pragma unroll
    for (int base = 0; base < 224; base += 32){
      int j = base + jj;
      u32x4 kv = {0,0,0,0}, vv = {0,0,0,0};
      if (j < 197){
        int t = (j == 0) ? 0 : (1 + fi*196 + j - 1);
        kv = *(const u32x4*)(kg + (size_t)t*64 + c);
        vv = *(const u32x4*)(vg + (size_t)t*64 + c);
      }
      if (j < 208) *(u32x4*)&Ks[j][c] = kv;
      int jl = j & 31;
      int col = (j & ~31) + ((jl & 15)*2 + (jl >> 4));
      const u16* vp = (const u16*)&vv;
      #pragma unroll
      for (int i=0;i<8;i++) Vt[c+i][col] = vp[i];
    }
  }

  s16x8 qf[4][2];
  #pragma unroll
  for (int mt=0; mt<4; mt++){
    int row = w*64 + mt*16 + l15;
    #pragma unroll
    for (int kk=0; kk<2; kk++){
      if (row < 196) qf[mt][kk] = ld16B(qg + (size_t)row*64 + kk*32 + l4*8);
      else { u32x4 z = {0,0,0,0}; qf[mt][kk] = __builtin_bit_cast(s16x8, z); }
    }
  }

  f32x4 acc[4][4];
  float rsum[4][4];
  #pragma unroll
  for (int a=0;a<4;a++)
    #pragma unroll
    for (int b=0;b<4;b++){ acc[a][b] = (f32x4){0.f,0.f,0.f,0.f}; rsum[a][b] = 0.f; }

  __syncthreads();

  for (int ck = 0; ck < 7; ck++){
    int r0 = ck*32 + l15;
    int r1 = r0 + 16; if (r1 > 207) r1 = 207;
    s16x8 kf0[2], kf1[2];
    #pragma unroll
    for (int kk=0; kk<2; kk++){
      kf0[kk] = ld16B(&Ks[r0][kk*32 + l4*8]);
      kf1[kk] = ld16B(&Ks[r1][kk*32 + l4*8]);
    }
    bool ok0 = (ck*32 + l15) < 197;
    bool ok1 = (ck*32 + 16 + l15) < 197;

    #pragma unroll
    for (int mt=0; mt<4; mt++){
      __builtin_amdgcn_s_setprio(1);
      f32x4 s0 = (f32x4){0.f,0.f,0.f,0.f}, s1 = (f32x4){0.f,0.f,0.f,0.f};
      s0 = mfma16(qf[mt][0], kf0[0], s0);
      s0 = mfma16(qf[mt][1], kf0[1], s0);
      s1 = mfma16(qf[mt][0], kf1[0], s1);
      s1 = mfma16(qf[mt][1], kf1[1], s1);
      __builtin_amdgcn_s_setprio(0);
      #pragma unroll
      for (int r=0; r<4; r++){
        float p0 = ok0 ? __expf(s0[r] - 8.f) : 0.f;
        float p1 = ok1 ? __expf(s1[r] - 8.f) : 0.f;
        rsum[mt][r] += p0 + p1;
        int prow = mt*16 + l4*4 + r;
        *(u32*)&Ps[w][prow][2*l15] = cvt_pk_bf16(p0, p1);
      }
    }

    s16x8 vf[4];
    #pragma unroll
    for (int ntd=0; ntd<4; ntd++) vf[ntd] = ld16B(&Vt[ntd*16 + l15][ck*32 + l4*8]);
    #pragma unroll
    for (int mt=0; mt<4; mt++){
      s16x8 pf = ld16B(&Ps[w][mt*16 + l15][l4*8]);
      __builtin_amdgcn_s_setprio(1);
      #pragma unroll
      for (int ntd=0; ntd<4; ntd++)
        acc[mt][ntd] = mfma16(pf, vf[ntd], acc[mt][ntd]);
      __builtin_amdgcn_s_setprio(0);
    }
  }

  u16* og = ob + ((size_t)bh*1569 + 1 + fi*196)*64;
  #pragma unroll
  for (int mt=0; mt<4; mt++){
    #pragma unroll
    for (int r=0; r<4; r++){
      float rs = rsum[mt][r];
      rs += __shfl_xor(rs, 1);
      rs += __shfl_xor(rs, 2);
      rs += __shfl_xor(rs, 4);
      rs += __shfl_xor(rs, 8);
      int row = w*64 + mt*16 + l4*4 + r;
      if (row < 196){
        float inv = 1.f / rs;
        #pragma unroll
        for (int ntd=0; ntd<4; ntd++)
          og[(size_t)row*64 + ntd*16 + l15] = f2bf(acc[mt][ntd][r] * inv);
      }
    }
  }
}

// ---------------- out GEMM: gather(attn_out) [12552x768] @ [768x768] + bias -> f32 ----------------
__global__ __launch_bounds__(256) void gemm_out(const u16* __restrict__ AO, const u16* __restrict__ BT,
                                                const float* __restrict__ bias, float* __restrict__ C){
  __shared__ u16 As[128*64];
  __shared__ u16 Bs[128*64];
  const int M = 12552;
  const int NWG = 6*99;
  int logical = xcd_chunk(blockIdx.x, NWG);
  int bxi = logical % 6, byi = logical / 6;
  int bm = byi * 128, bn = bxi * 128;

  int tid = threadIdx.x;
  int w = tid >> 6, l = tid & 63, l15 = l & 15, l4 = l >> 4;
  int wr = w >> 1, wc = w & 1;
  f32x4 acc[4][4];
  #pragma unroll
  for (int a=0;a<4;a++)
    #pragma unroll
    for (int b=0;b<4;b++) acc[a][b] = (f32x4){0.f,0.f,0.f,0.f};

  int srow = l >> 3;
  int scol = (l & 7) * 8;

  for (int kt = 0; kt < 12; kt++){
    #pragma unroll
    for (int p = 0; p < 4; p++){
      int i = w*4 + p;
      int row = i*8 + srow;
      int gr = bm + row; if (gr >= M) gr = M-1;
      int b = gr / 1569, t = gr - b*1569;
      gload16(AO + ((size_t)(b*12 + kt)*1569 + t)*64 + scol, &As[i*512]);
      gload16(BT + (size_t)(bn+row)*768 + kt*64 + scol, &Bs[i*512]);
    }
    __syncthreads();
    #pragma unroll
    for (int kk = 0; kk < 2; kk++){
      s16x8 af[4], bfr[4];
      #pragma unroll
      for (int mt=0; mt<4; mt++) af[mt]  = ld16B(&As[(wr*64 + mt*16 + l15)*64 + kk*32 + l4*8]);
      #pragma unroll
      for (int nt=0; nt<4; nt++) bfr[nt] = ld16B(&Bs[(wc*64 + nt*16 + l15)*64 + kk*32 + l4*8]);
      #pragma unroll
      for (int mt=0; mt<4; mt++)
        #pragma unroll
        for (int nt=0; nt<4; nt++)
          acc[mt][nt] = mfma16(af[mt], bfr[nt], acc[mt][nt]);
    }
    __syncthreads();
  }

  #pragma unroll
  for (int mt=0; mt<4; mt++){
    #pragma unroll
    for (int r=0; r<4; r++){
      int m = bm + wr*64 + mt*16 + l4*4 + r;
      if (m >= M) continue;
      #pragma unroll
      for (int nt=0; nt<4; nt++){
        int n = bn + wc*64 + nt*16 + l15;
        C[(size_t)m*768 + n] = acc[mt][nt][r] + bias[n];
      }
    }
  }
}

extern "C" void kernel_launch(void* const* d_in, const int* in_sizes, int n_in,
                              void* d_out, int out_size, void* d_ws, size_t ws_size,
                              hipStream_t stream){
  (void)in_sizes; (void)n_in; (void)out_size;
  const float* x    = (const float*)d_in[0];
  const float* Wqkv = (const float*)d_in[1];
  const float* Wout = (const float*)d_in[2];
  const float* bout = (const float*)d_in[3];
  float* out0 = (float*)d_out;
  float* out1 = out0 + (size_t)12552*768;   // cls_attn (96*1569)

  char* ws = (char*)d_ws;
  size_t off = 0;
  auto alloc = [&](size_t bytes)->char*{
    char* p = ws + off;
    off += (bytes + 255) & ~(size_t)255;
    return p;
  };
  u16* xb    = (u16*)alloc((size_t)12552*768*2);
  u16* wqkvT = (u16*)alloc((size_t)2304*768*2);
  u16* woutT = (u16*)alloc((size_t)768*768*2);
  u16* qb    = (u16*)alloc((size_t)96*1569*64*2);
  u16* kbuf  = (u16*)alloc((size_t)96*1569*64*2);
  u16* vbuf  = (u16*)alloc((size_t)96*1569*64*2);
  u16* ao    = (u16*)alloc((size_t)96*1569*64*2);
  float* simw = (float*)alloc((size_t)96*1569*4);
  float* bmax = (float*)alloc((size_t)96*8*4);
  float* pvp  = (float*)alloc((size_t)96*7*64*4);
  if (off > ws_size) return;

  k_cvt<<<2048, 256, 0, stream>>>(x, xb, 12552*768/4);
  k_transpose<<<dim3(72, 24), 256, 0, stream>>>(Wqkv, wqkvT, 768, 2304);
  k_transpose<<<dim3(24, 24), 256, 0, stream>>>(Wout, woutT, 768, 768);
  gemm_qkv<<<50*9, 512, 0, stream>>>(xb, wqkvT, qb, kbuf, vbuf);
  cls_sim<<<dim3(7, 96), 256, 0, stream>>>(qb, kbuf, simw, bmax);
  cls_fin<<<96, 256, 0, stream>>>(simw, bmax, out1);
  cls_pv<<<dim3(7, 96), 256, 0, stream>>>(out1, vbuf, pvp);
  cls_pv_red<<<96, 64, 0, stream>>>(pvp, ao);
  k_frame<<<768, 256, 0, stream>>>(qb, kbuf, vbuf, ao);
  gemm_out<<<6*99, 256, 0, stream>>>(ao, woutT, bout, out0);
}

// Round 6
// 183.539 us; speedup vs baseline: 1.9281x; 1.0564x over previous
//
#include <hip/hip_runtime.h>

typedef unsigned short u16;
typedef unsigned int u32;
typedef __attribute__((ext_vector_type(8))) short s16x8;   // 8 bf16 (4 VGPR) MFMA frag
typedef __attribute__((ext_vector_type(4))) float f32x4;
typedef __attribute__((ext_vector_type(4))) u32 u32x4;
typedef __attribute__((ext_vector_type(4))) float fvec4;

#define DEV static __device__ __forceinline__

typedef __attribute__((address_space(1))) unsigned char ga_u8;
typedef __attribute__((address_space(3))) unsigned char la_u8;

DEV u16 f2bf(float f){
  u32 u = __builtin_bit_cast(u32, f);
  u32 r = (u + 0x7FFFu + ((u >> 16) & 1u)) >> 16;
  return (u16)r;
}
DEV float bf2f(u16 v){
  u32 x = ((u32)v) << 16;
  return __builtin_bit_cast(float, x);
}
DEV f32x4 mfma16(s16x8 a, s16x8 b, f32x4 c){
  return __builtin_amdgcn_mfma_f32_16x16x32_bf16(a, b, c, 0, 0, 0);
}
DEV s16x8 ld16B(const u16* p){
  return __builtin_bit_cast(s16x8, *(const u32x4*)p);
}
DEV u32 cvt_pk_bf16(float lo, float hi){
  u32 r;
  asm volatile("v_cvt_pk_bf16_f32 %0, %1, %2" : "=v"(r) : "v"(lo), "v"(hi));
  return r;
}
DEV void gload16(const void* g, void* l){
  __builtin_amdgcn_global_load_lds((const ga_u8*)g, (la_u8*)l, 16, 0, 0);
}
DEV int xcd_chunk(int bid, int nwg){
  int q = nwg >> 3, r = nwg & 7;
  int xcd = bid & 7, lin = bid >> 3;
  return (xcd < r ? xcd*(q+1) : r*(q+1) + (xcd-r)*q) + lin;
}

#define BARRIER() __builtin_amdgcn_s_barrier()
#define LGKM0()   asm volatile("s_waitcnt lgkmcnt(0)" ::: "memory")
#define VMC4()    asm volatile("s_waitcnt vmcnt(4)" ::: "memory")
#define VMC0()    asm volatile("s_waitcnt vmcnt(0)" ::: "memory")

// Problem sizes: B=8 NT=1569 DIM=768 H=12 D=64 BH=96 F=8 NQ=196 M=12552 Nqkv=2304 K=768

// ---------------- conversion kernels ----------------
__global__ __launch_bounds__(256) void k_cvt(const float* __restrict__ in, u16* __restrict__ out, int n4){
  int i = blockIdx.x*256 + threadIdx.x;
  int stride = gridDim.x*256;
  for (; i < n4; i += stride){
    fvec4 v = ((const fvec4*)in)[i];
    u16 o0 = f2bf(v[0]), o1 = f2bf(v[1]), o2 = f2bf(v[2]), o3 = f2bf(v[3]);
    u32 lo = (u32)o0 | ((u32)o1 << 16);
    u32 hi = (u32)o2 | ((u32)o3 << 16);
    ((u32*)out)[2*i]   = lo;
    ((u32*)out)[2*i+1] = hi;
  }
}

// W[K][N] f32 -> WT[N][K] bf16, LDS-tiled
__global__ __launch_bounds__(256) void k_transpose(const float* __restrict__ W, u16* __restrict__ WT, int K, int N){
  __shared__ float tile[32][33];
  int bn = blockIdx.x * 32;
  int bk = blockIdx.y * 32;
  int tx = threadIdx.x & 31, ty = threadIdx.x >> 5;
  #pragma unroll
  for (int r = ty; r < 32; r += 8)
    tile[r][tx] = W[(size_t)(bk + r)*N + bn + tx];
  __syncthreads();
  #pragma unroll
  for (int r = ty; r < 32; r += 8)
    WT[(size_t)(bn + r)*K + bk + tx] = f2bf(tile[tx][r]);
}

// ---------------- QKV GEMM, 256x256 8-phase schedule (T1+T2+T3+T4+T5) ----------------
// (verified R5: bank-conflict 0, 67 us) — unchanged this round.
__global__ __launch_bounds__(512, 2) void gemm_qkv(const u16* __restrict__ A, const u16* __restrict__ BT,
                                                   u16* __restrict__ qout, u16* __restrict__ kout, u16* __restrict__ vout){
  __shared__ u16 sA[2][2][128*64];
  __shared__ u16 sB[2][2][128*64];
  const int M = 12552;
  const int NWG = 50*9;
  int logical = xcd_chunk(blockIdx.x, NWG);
  int bxi = logical % 9, byi = logical / 9;
  int bm = byi * 256, bn = bxi * 256;

  int tid = threadIdx.x;
  int w = tid >> 6, l = tid & 63, l15 = l & 15, l4 = l >> 4;
  int wm = w >> 2, wn = w & 3;
  int swz = (l15 & 7) << 3;

  f32x4 acc[8][4];
  #pragma unroll
  for (int a=0;a<8;a++)
    #pragma unroll
    for (int b=0;b<4;b++) acc[a][b] = (f32x4){0.f,0.f,0.f,0.f};

  auto stageA = [&](int dbuf, int h, int kt){
    #pragma unroll
    for (int i=0;i<2;i++){
      int ci = i*512 + tid;
      int cs = ci ^ ((ci>>3)&7);
      int r = cs>>3, cc = (cs&7)*8;
      int gr = bm + h*128 + r; if (gr >= M) gr = M-1;
      gload16(A + (size_t)gr*768 + kt*64 + cc, &sA[dbuf][h][(i*512 + (w<<6))*8]);
    }
  };
  auto stageB = [&](int dbuf, int h, int kt){
    #pragma unroll
    for (int i=0;i<2;i++){
      int ci = i*512 + tid;
      int cs = ci ^ ((ci>>3)&7);
      int r = cs>>3, cc = (cs&7)*8;
      gload16(BT + (size_t)(bn + h*128 + r)*768 + kt*64 + cc, &sB[dbuf][h][(i*512 + (w<<6))*8]);
    }
  };

  s16x8 af[4][2], bf[4][2];
  #define LDA_(d, mi, kk) ld16B(&sA[d][wm][(((mi)*16 + l15)*64 + (kk)*32 + l4*8) ^ swz])
  #define LDB_(d, ni, kk) ld16B(&sB[d][(wn*64 + (ni)*16 + l15)>>7][((((wn*64 + (ni)*16 + l15)&127))*64 + (kk)*32 + l4*8) ^ swz])
  #define QUAD(MH, NH) do{ \
    __builtin_amdgcn_s_setprio(1); \
    _Pragma("unroll") \
    for (int j=0;j<4;j++){ \
      _Pragma("unroll") \
      for (int n=0;n<2;n++){ \
        acc[(MH)*4+j][(NH)*2+n] = mfma16(af[j][0], bf[(NH)*2+n][0], acc[(MH)*4+j][(NH)*2+n]); \
        acc[(MH)*4+j][(NH)*2+n] = mfma16(af[j][1], bf[(NH)*2+n][1], acc[(MH)*4+j][(NH)*2+n]); \
      } } \
    __builtin_amdgcn_s_setprio(0); }while(0)

  stageA(0,0,0); stageA(0,1,0); stageB(0,0,0); stageB(0,1,0);
  stageA(1,0,1); stageA(1,1,1);
  VMC4();
  BARRIER();

  #pragma unroll 1
  for (int it = 0; it < 6; ++it){
    int kt1 = 2*it + 1;
    bool full = (it < 5);
    #pragma unroll
    for (int j=0;j<4;j++){ af[j][0]=LDA_(0,j,0); af[j][1]=LDA_(0,j,1); }
    #pragma unroll
    for (int n=0;n<2;n++){ bf[n][0]=LDB_(0,n,0); bf[n][1]=LDB_(0,n,1); }
    stageB(1, 0, kt1);
    BARRIER(); LGKM0();
    QUAD(0,0);
    BARRIER();
    #pragma unroll
    for (int n=2;n<4;n++){ bf[n][0]=LDB_(0,n,0); bf[n][1]=LDB_(0,n,1); }
    stageB(1, 1, kt1);
    BARRIER(); LGKM0();
    QUAD(0,1);
    BARRIER();
    #pragma unroll
    for (int j=0;j<4;j++){ af[j][0]=LDA_(0,4+j,0); af[j][1]=LDA_(0,4+j,1); }
    if (full) stageA(0, 0, kt1+1);
    BARRIER(); LGKM0();
    QUAD(1,0);
    BARRIER();
    if (full) stageA(0, 1, kt1+1);
    BARRIER();
    QUAD(1,1);
    if (full) { VMC4(); } else { VMC0(); }
    BARRIER();
    #pragma unroll
    for (int j=0;j<4;j++){ af[j][0]=LDA_(1,j,0); af[j][1]=LDA_(1,j,1); }
    #pragma unroll
    for (int n=0;n<2;n++){ bf[n][0]=LDB_(1,n,0); bf[n][1]=LDB_(1,n,1); }
    if (full) stageB(0, 0, kt1+1);
    BARRIER(); LGKM0();
    QUAD(0,0);
    BARRIER();
    #pragma unroll
    for (int n=2;n<4;n++){ bf[n][0]=LDB_(1,n,0); bf[n][1]=LDB_(1,n,1); }
    if (full) stageB(0, 1, kt1+1);
    BARRIER(); LGKM0();
    QUAD(0,1);
    BARRIER();
    #pragma unroll
    for (int j=0;j<4;j++){ af[j][0]=LDA_(1,4+j,0); af[j][1]=LDA_(1,4+j,1); }
    if (full) stageA(1, 0, kt1+2);
    BARRIER(); LGKM0();
    QUAD(1,0);
    BARRIER();
    if (full) stageA(1, 1, kt1+2);
    BARRIER();
    QUAD(1,1);
    if (full) VMC4();
    BARRIER();
  }
  #undef LDA_
  #undef LDB_
  #undef QUAD

  int which = bn / 768;
  int h = ((bn - which*768) >> 6) + wn;
  u16* dst  = (which==0) ? qout : ((which==1) ? kout : vout);
  float scale = (which==0) ? 0.125f : 1.f;
  #pragma unroll
  for (int mi=0; mi<8; mi++){
    #pragma unroll
    for (int r=0; r<4; r++){
      int m = bm + wm*128 + mi*16 + l4*4 + r;
      if (m >= M) continue;
      int b = m / 1569, t = m - b*1569;
      u16* drow = dst + ((size_t)(b*12 + h)*1569 + t)*64 + l15;
      #pragma unroll
      for (int n=0; n<4; n++)
        drow[n*16] = f2bf(acc[mi][n][r] * scale);
    }
  }
}

// ---------------- CLS attention, parallelized ----------------
__global__ __launch_bounds__(256) void cls_sim(const u16* __restrict__ qb, const u16* __restrict__ kb,
                                               float* __restrict__ sim, float* __restrict__ bmax){
  int c = blockIdx.x, g = blockIdx.y;
  int tid = threadIdx.x;
  __shared__ float qv[64];
  __shared__ float red[256];
  if (tid < 64) qv[tid] = bf2f(qb[(size_t)g*1569*64 + tid]);
  __syncthreads();
  int j = c*256 + tid;
  float s = -1e30f;
  if (j < 1569){
    const u16* kr = kb + ((size_t)g*1569 + j)*64;
    float a = 0.f;
    #pragma unroll
    for (int d0 = 0; d0 < 64; d0 += 8){
      u32x4 u = *(const u32x4*)(kr + d0);
      const u16* us = (const u16*)&u;
      #pragma unroll
      for (int i=0;i<8;i++) a += qv[d0+i]*bf2f(us[i]);
    }
    s = a;
    sim[(size_t)g*1569 + j] = s;
  }
  red[tid] = s; __syncthreads();
  for (int st=128; st>0; st>>=1){ if (tid<st) red[tid] = fmaxf(red[tid], red[tid+st]); __syncthreads(); }
  if (tid == 0) bmax[g*8 + c] = red[0];
}

__global__ __launch_bounds__(256) void cls_fin(float* __restrict__ sim, const float* __restrict__ bmax,
                                               float* __restrict__ attn){
  int g = blockIdx.x, tid = threadIdx.x;
  __shared__ float red[256];
  float m = -1e30f;
  #pragma unroll
  for (int c=0;c<7;c++) m = fmaxf(m, bmax[g*8+c]);
  float ls = 0.f;
  for (int j = tid; j < 1569; j += 256){
    float e = expf(sim[(size_t)g*1569+j] - m);
    sim[(size_t)g*1569+j] = e;
    ls += e;
  }
  red[tid] = ls; __syncthreads();
  for (int st=128; st>0; st>>=1){ if (tid<st) red[tid] += red[tid+st]; __syncthreads(); }
  float inv = 1.f/red[0];
  for (int j = tid; j < 1569; j += 256)
    attn[(size_t)g*1569+j] = sim[(size_t)g*1569+j]*inv;
}

__global__ __launch_bounds__(256) void cls_pv(const float* __restrict__ attn, const u16* __restrict__ vb,
                                              float* __restrict__ pvp){
  int c = blockIdx.x, g = blockIdx.y;
  int tid = threadIdx.x;
  int d = tid & 63, kk = tid >> 6;
  __shared__ float red[256];
  float a = 0.f;
  for (int jj = kk; jj < 256; jj += 4){
    int j = c*256 + jj;
    if (j < 1569) a += attn[(size_t)g*1569+j] * bf2f(vb[((size_t)g*1569+j)*64 + d]);
  }
  red[tid] = a; __syncthreads();
  if (tid < 64) pvp[((size_t)g*7 + c)*64 + tid] = red[tid]+red[tid+64]+red[tid+128]+red[tid+192];
}

__global__ __launch_bounds__(64) void cls_pv_red(const float* __restrict__ pvp, u16* __restrict__ ob){
  int g = blockIdx.x, d = threadIdx.x;
  float s = 0.f;
  #pragma unroll
  for (int c=0;c<7;c++) s += pvp[((size_t)g*7+c)*64 + d];
  ob[(size_t)g*1569*64 + d] = f2bf(s);
}

// ---------------- frame attention: full-KV-in-LDS, fixed-shift softmax ----------------
__global__ __launch_bounds__(256) void k_frame(const u16* __restrict__ qb, const u16* __restrict__ kb,
                                               const u16* __restrict__ vb, u16* __restrict__ ob){
  int g = blockIdx.x;
  int bh = g >> 3, fi = g & 7;
  int tid = threadIdx.x;
  int w = tid >> 6, l = tid & 63;
  int l15 = l & 15, l4 = l >> 4;

  __shared__ u16 Ks[208][72];
  __shared__ u16 Vt[64][232];
  __shared__ u16 Ps[4][64][40];

  const u16* qg = qb + ((size_t)bh*1569 + 1 + fi*196)*64;
  const u16* kg = kb + (size_t)bh*1569*64;
  const u16* vg = vb + (size_t)bh*1569*64;

  {
    int jj = tid >> 3, c = (tid & 7)*8;
    #pragma unroll
    for (int base = 0; base < 224; base += 32){
      int j = base + jj;
      u32x4 kv = {0,0,0,0}, vv = {0,0,0,0};
      if (j < 197){
        int t = (j == 0) ? 0 : (1 + fi*196 + j - 1);
        kv = *(const u32x4*)(kg + (size_t)t*64 + c);
        vv = *(const u32x4*)(vg + (size_t)t*64 + c);
      }
      if (j < 208) *(u32x4*)&Ks[j][c] = kv;
      int jl = j & 31;
      int col = (j & ~31) + ((jl & 15)*2 + (jl >> 4));
      const u16* vp = (const u16*)&vv;
      #pragma unroll
      for (int i=0;i<8;i++) Vt[c+i][col] = vp[i];
    }
  }

  s16x8 qf[4][2];
  #pragma unroll
  for (int mt=0; mt<4; mt++){
    int row = w*64 + mt*16 + l15;
    #pragma unroll
    for (int kk=0; kk<2; kk++){
      if (row < 196) qf[mt][kk] = ld16B(qg + (size_t)row*64 + kk*32 + l4*8);
      else { u32x4 z = {0,0,0,0}; qf[mt][kk] = __builtin_bit_cast(s16x8, z); }
    }
  }

  f32x4 acc[4][4];
  float rsum[4][4];
  #pragma unroll
  for (int a=0;a<4;a++)
    #pragma unroll
    for (int b=0;b<4;b++){ acc[a][b] = (f32x4){0.f,0.f,0.f,0.f}; rsum[a][b] = 0.f; }

  __syncthreads();

  for (int ck = 0; ck < 7; ck++){
    int r0 = ck*32 + l15;
    int r1 = r0 + 16; if (r1 > 207) r1 = 207;
    s16x8 kf0[2], kf1[2];
    #pragma unroll
    for (int kk=0; kk<2; kk++){
      kf0[kk] = ld16B(&Ks[r0][kk*32 + l4*8]);
      kf1[kk] = ld16B(&Ks[r1][kk*32 + l4*8]);
    }
    bool ok0 = (ck*32 + l15) < 197;
    bool ok1 = (ck*32 + 16 + l15) < 197;

    #pragma unroll
    for (int mt=0; mt<4; mt++){
      __builtin_amdgcn_s_setprio(1);
      f32x4 s0 = (f32x4){0.f,0.f,0.f,0.f}, s1 = (f32x4){0.f,0.f,0.f,0.f};
      s0 = mfma16(qf[mt][0], kf0[0], s0);
      s0 = mfma16(qf[mt][1], kf0[1], s0);
      s1 = mfma16(qf[mt][0], kf1[0], s1);
      s1 = mfma16(qf[mt][1], kf1[1], s1);
      __builtin_amdgcn_s_setprio(0);
      #pragma unroll
      for (int r=0; r<4; r++){
        float p0 = ok0 ? __expf(s0[r] - 8.f) : 0.f;
        float p1 = ok1 ? __expf(s1[r] - 8.f) : 0.f;
        rsum[mt][r] += p0 + p1;
        int prow = mt*16 + l4*4 + r;
        *(u32*)&Ps[w][prow][2*l15] = cvt_pk_bf16(p0, p1);
      }
    }

    s16x8 vf[4];
    #pragma unroll
    for (int ntd=0; ntd<4; ntd++) vf[ntd] = ld16B(&Vt[ntd*16 + l15][ck*32 + l4*8]);
    #pragma unroll
    for (int mt=0; mt<4; mt++){
      s16x8 pf = ld16B(&Ps[w][mt*16 + l15][l4*8]);
      __builtin_amdgcn_s_setprio(1);
      #pragma unroll
      for (int ntd=0; ntd<4; ntd++)
        acc[mt][ntd] = mfma16(pf, vf[ntd], acc[mt][ntd]);
      __builtin_amdgcn_s_setprio(0);
    }
  }

  u16* og = ob + ((size_t)bh*1569 + 1 + fi*196)*64;
  #pragma unroll
  for (int mt=0; mt<4; mt++){
    #pragma unroll
    for (int r=0; r<4; r++){
      float rs = rsum[mt][r];
      rs += __shfl_xor(rs, 1);
      rs += __shfl_xor(rs, 2);
      rs += __shfl_xor(rs, 4);
      rs += __shfl_xor(rs, 8);
      int row = w*64 + mt*16 + l4*4 + r;
      if (row < 196){
        float inv = 1.f / rs;
        #pragma unroll
        for (int ntd=0; ntd<4; ntd++)
          og[(size_t)row*64 + ntd*16 + l15] = f2bf(acc[mt][ntd][r] * inv);
      }
    }
  }
}

// ---------------- out GEMM, 256x256 8-phase (same verified template) ----------------
// gather(attn_out) [12552x768] @ [768x768] + bias -> f32. BK=64 == one head for
// the A-gather (kt == head). Grid 50x3 = 150 blocks -> 1 block/CU, no tail.
__global__ __launch_bounds__(512, 2) void gemm_out(const u16* __restrict__ AO, const u16* __restrict__ BT,
                                                   const float* __restrict__ bias, float* __restrict__ C){
  __shared__ u16 sA[2][2][128*64];
  __shared__ u16 sB[2][2][128*64];
  const int M = 12552;
  const int NWG = 50*3;
  int logical = xcd_chunk(blockIdx.x, NWG);
  int bxi = logical % 3, byi = logical / 3;
  int bm = byi * 256, bn = bxi * 256;

  int tid = threadIdx.x;
  int w = tid >> 6, l = tid & 63, l15 = l & 15, l4 = l >> 4;
  int wm = w >> 2, wn = w & 3;
  int swz = (l15 & 7) << 3;

  f32x4 acc[8][4];
  #pragma unroll
  for (int a=0;a<8;a++)
    #pragma unroll
    for (int b=0;b<4;b++) acc[a][b] = (f32x4){0.f,0.f,0.f,0.f};

  auto stageA = [&](int dbuf, int h, int kt){
    #pragma unroll
    for (int i=0;i<2;i++){
      int ci = i*512 + tid;
      int cs = ci ^ ((ci>>3)&7);
      int r = cs>>3, cc = (cs&7)*8;
      int gr = bm + h*128 + r; if (gr >= M) gr = M-1;
      int b = gr / 1569, t = gr - b*1569;
      gload16(AO + ((size_t)(b*12 + kt)*1569 + t)*64 + cc, &sA[dbuf][h][(i*512 + (w<<6))*8]);
    }
  };
  auto stageB = [&](int dbuf, int h, int kt){
    #pragma unroll
    for (int i=0;i<2;i++){
      int ci = i*512 + tid;
      int cs = ci ^ ((ci>>3)&7);
      int r = cs>>3, cc = (cs&7)*8;
      gload16(BT + (size_t)(bn + h*128 + r)*768 + kt*64 + cc, &sB[dbuf][h][(i*512 + (w<<6))*8]);
    }
  };

  s16x8 af[4][2], bf[4][2];
  #define LDA_(d, mi, kk) ld16B(&sA[d][wm][(((mi)*16 + l15)*64 + (kk)*32 + l4*8) ^ swz])
  #define LDB_(d, ni, kk) ld16B(&sB[d][(wn*64 + (ni)*16 + l15)>>7][((((wn*64 + (ni)*16 + l15)&127))*64 + (kk)*32 + l4*8) ^ swz])
  #define QUAD(MH, NH) do{ \
    __builtin_amdgcn_s_setprio(1); \
    _Pragma("unroll") \
    for (int j=0;j<4;j++){ \
      _Pragma("unroll") \
      for (int n=0;n<2;n++){ \
        acc[(MH)*4+j][(NH)*2+n] = mfma16(af[j][0], bf[(NH)*2+n][0], acc[(MH)*4+j][(NH)*2+n]); \
        acc[(MH)*4+j][(NH)*2+n] = mfma16(af[j][1], bf[(NH)*2+n][1], acc[(MH)*4+j][(NH)*2+n]); \
      } } \
    __builtin_amdgcn_s_setprio(0); }while(0)

  stageA(0,0,0); stageA(0,1,0); stageB(0,0,0); stageB(0,1,0);
  stageA(1,0,1); stageA(1,1,1);
  VMC4();
  BARRIER();

  #pragma unroll 1
  for (int it = 0; it < 6; ++it){
    int kt1 = 2*it + 1;
    bool full = (it < 5);
    #pragma unroll
    for (int j=0;j<4;j++){ af[j][0]=LDA_(0,j,0); af[j][1]=LDA_(0,j,1); }
    #pragma unroll
    for (int n=0;n<2;n++){ bf[n][0]=LDB_(0,n,0); bf[n][1]=LDB_(0,n,1); }
    stageB(1, 0, kt1);
    BARRIER(); LGKM0();
    QUAD(0,0);
    BARRIER();
    #pragma unroll
    for (int n=2;n<4;n++){ bf[n][0]=LDB_(0,n,0); bf[n][1]=LDB_(0,n,1); }
    stageB(1, 1, kt1);
    BARRIER(); LGKM0();
    QUAD(0,1);
    BARRIER();
    #pragma unroll
    for (int j=0;j<4;j++){ af[j][0]=LDA_(0,4+j,0); af[j][1]=LDA_(0,4+j,1); }
    if (full) stageA(0, 0, kt1+1);
    BARRIER(); LGKM0();
    QUAD(1,0);
    BARRIER();
    if (full) stageA(0, 1, kt1+1);
    BARRIER();
    QUAD(1,1);
    if (full) { VMC4(); } else { VMC0(); }
    BARRIER();
    #pragma unroll
    for (int j=0;j<4;j++){ af[j][0]=LDA_(1,j,0); af[j][1]=LDA_(1,j,1); }
    #pragma unroll
    for (int n=0;n<2;n++){ bf[n][0]=LDB_(1,n,0); bf[n][1]=LDB_(1,n,1); }
    if (full) stageB(0, 0, kt1+1);
    BARRIER(); LGKM0();
    QUAD(0,0);
    BARRIER();
    #pragma unroll
    for (int n=2;n<4;n++){ bf[n][0]=LDB_(1,n,0); bf[n][1]=LDB_(1,n,1); }
    if (full) stageB(0, 1, kt1+1);
    BARRIER(); LGKM0();
    QUAD(0,1);
    BARRIER();
    #pragma unroll
    for (int j=0;j<4;j++){ af[j][0]=LDA_(1,4+j,0); af[j][1]=LDA_(1,4+j,1); }
    if (full) stageA(1, 0, kt1+2);
    BARRIER(); LGKM0();
    QUAD(1,0);
    BARRIER();
    if (full) stageA(1, 1, kt1+2);
    BARRIER();
    QUAD(1,1);
    if (full) VMC4();
    BARRIER();
  }
  #undef LDA_
  #undef LDB_
  #undef QUAD

  // epilogue: f32 + bias, coalesced 16-consecutive-f32 per 16-lane group
  int n0 = bn + wn*64;
  float bv[4];
  #pragma unroll
  for (int n=0;n<4;n++) bv[n] = bias[n0 + n*16 + l15];
  #pragma unroll
  for (int mi=0; mi<8; mi++){
    #pragma unroll
    for (int r=0; r<4; r++){
      int m = bm + wm*128 + mi*16 + l4*4 + r;
      if (m >= M) continue;
      float* crow = C + (size_t)m*768 + n0 + l15;
      #pragma unroll
      for (int n=0; n<4; n++)
        crow[n*16] = acc[mi][n][r] + bv[n];
    }
  }
}

extern "C" void kernel_launch(void* const* d_in, const int* in_sizes, int n_in,
                              void* d_out, int out_size, void* d_ws, size_t ws_size,
                              hipStream_t stream){
  (void)in_sizes; (void)n_in; (void)out_size;
  const float* x    = (const float*)d_in[0];
  const float* Wqkv = (const float*)d_in[1];
  const float* Wout = (const float*)d_in[2];
  const float* bout = (const float*)d_in[3];
  float* out0 = (float*)d_out;
  float* out1 = out0 + (size_t)12552*768;   // cls_attn (96*1569)

  char* ws = (char*)d_ws;
  size_t off = 0;
  auto alloc = [&](size_t bytes)->char*{
    char* p = ws + off;
    off += (bytes + 255) & ~(size_t)255;
    return p;
  };
  u16* xb    = (u16*)alloc((size_t)12552*768*2);
  u16* wqkvT = (u16*)alloc((size_t)2304*768*2);
  u16* woutT = (u16*)alloc((size_t)768*768*2);
  u16* qb    = (u16*)alloc((size_t)96*1569*64*2);
  u16* kbuf  = (u16*)alloc((size_t)96*1569*64*2);
  u16* vbuf  = (u16*)alloc((size_t)96*1569*64*2);
  u16* ao    = (u16*)alloc((size_t)96*1569*64*2);
  float* simw = (float*)alloc((size_t)96*1569*4);
  float* bmax = (float*)alloc((size_t)96*8*4);
  float* pvp  = (float*)alloc((size_t)96*7*64*4);
  if (off > ws_size) return;

  k_cvt<<<2048, 256, 0, stream>>>(x, xb, 12552*768/4);
  k_transpose<<<dim3(72, 24), 256, 0, stream>>>(Wqkv, wqkvT, 768, 2304);
  k_transpose<<<dim3(24, 24), 256, 0, stream>>>(Wout, woutT, 768, 768);
  gemm_qkv<<<50*9, 512, 0, stream>>>(xb, wqkvT, qb, kbuf, vbuf);
  cls_sim<<<dim3(7, 96), 256, 0, stream>>>(qb, kbuf, simw, bmax);
  cls_fin<<<96, 256, 0, stream>>>(simw, bmax, out1);
  cls_pv<<<dim3(7, 96), 256, 0, stream>>>(out1, vbuf, pvp);
  cls_pv_red<<<96, 64, 0, stream>>>(pvp, ao);
  k_frame<<<768, 256, 0, stream>>>(qb, kbuf, vbuf, ao);
  gemm_out<<<50*3, 512, 0, stream>>>(ao, woutT, bout, out0);
}